// Round 8
// baseline (124.072 us; speedup 1.0000x reference)
//
#include <hip/hip_runtime.h>
#include <hip/hip_bf16.h>
#include <math.h>

#define B_ 2
#define T_ 512
#define D_ 64
#define NBLK_PER_B 1088   // sum_{jt=0..15} (8*jt+8)

typedef __attribute__((ext_vector_type(8))) short bf16x8;
typedef __attribute__((ext_vector_type(8))) unsigned short u16x8;
typedef __attribute__((ext_vector_type(4))) float f32x4;

static __device__ __forceinline__ unsigned short f2bf(float v) {
    __hip_bfloat16 h = __float2bfloat16(v);
    return *reinterpret_cast<unsigned short*>(&h);
}
static __device__ __forceinline__ float bf2f(unsigned short u) {
    return __uint_as_float(((unsigned)u) << 16);
}
static __device__ __forceinline__ unsigned short maxbits(unsigned short a, unsigned short b) {
    float m = fmaxf(bf2f(a), bf2f(b));
    return (unsigned short)(__float_as_uint(m) >> 16);
}
static __device__ __forceinline__ unsigned short minbits(unsigned short a, unsigned short b) {
    float m = fminf(bf2f(a), bf2f(b));
    return (unsigned short)(__float_as_uint(m) >> 16);
}

// ---------------------------------------------------------------------------
// Fused prep (267 heterogeneous blocks, 512 threads):
//  [0,8)    sparse tables tab[k][b][t][c], k=0..9, bf16
//  [8,11)   W fragment pack (full K)
//  [11,139) cur0bf[b][t][128] = bf16 suffix max/min of f (Hillis-Steele)
//  [139,171) intra[b][jt][jj][128] = running max/min within 32-j tile (scan)
//  [171,267) zero cur1 / cur2 / out
// ---------------------------------------------------------------------------
__global__ __launch_bounds__(512) void prep_kernel(
    const float* __restrict__ f,
    const float* __restrict__ W0, const float* __restrict__ W1, const float* __restrict__ W2,
    unsigned short* __restrict__ tmax, unsigned short* __restrict__ tmin,
    unsigned short* __restrict__ wf,
    unsigned short* __restrict__ cur0bf, unsigned short* __restrict__ intra,
    float* __restrict__ z0, float* __restrict__ z1, float* __restrict__ z2) {

    __shared__ unsigned short lmax[512][16];
    __shared__ unsigned short lmin[512][16];

    const int blk = blockIdx.x;
    const int tid = threadIdx.x;

    if (blk < 8) {
        const int b = blk & 1;
        const int c0 = (blk >> 1) * 16;
        const int t = tid;

        u16x8 mx[2], mn[2];
#pragma unroll
        for (int h = 0; h < 2; ++h) {
            const float* fp = &f[((size_t)(b * T_ + t) << 6) + c0 + h * 8];
#pragma unroll
            for (int e = 0; e < 8; ++e) {
                unsigned short u = f2bf(fp[e]);
                mx[h][e] = u; mn[h][e] = u;
            }
            size_t base = ((size_t)(b * T_ + t) << 6) + c0 + h * 8;
            *reinterpret_cast<u16x8*>(&tmax[base]) = mx[h];
            *reinterpret_cast<u16x8*>(&tmin[base]) = mn[h];
        }
        for (int k = 1; k <= 9; ++k) {
            *reinterpret_cast<u16x8*>(&lmax[t][0]) = mx[0];
            *reinterpret_cast<u16x8*>(&lmax[t][8]) = mx[1];
            *reinterpret_cast<u16x8*>(&lmin[t][0]) = mn[0];
            *reinterpret_cast<u16x8*>(&lmin[t][8]) = mn[1];
            __syncthreads();
            int t2 = t + (1 << (k - 1));
            if (t2 > T_ - 1) t2 = T_ - 1;
            u16x8 qx0 = *reinterpret_cast<const u16x8*>(&lmax[t2][0]);
            u16x8 qx1 = *reinterpret_cast<const u16x8*>(&lmax[t2][8]);
            u16x8 qn0 = *reinterpret_cast<const u16x8*>(&lmin[t2][0]);
            u16x8 qn1 = *reinterpret_cast<const u16x8*>(&lmin[t2][8]);
#pragma unroll
            for (int e = 0; e < 8; ++e) {
                mx[0][e] = maxbits(mx[0][e], qx0[e]);
                mx[1][e] = maxbits(mx[1][e], qx1[e]);
                mn[0][e] = minbits(mn[0][e], qn0[e]);
                mn[1][e] = minbits(mn[1][e], qn1[e]);
            }
            size_t base = ((size_t)((k * B_ + b) * T_ + t) << 6) + c0;
            *reinterpret_cast<u16x8*>(&tmax[base]) = mx[0];
            *reinterpret_cast<u16x8*>(&tmax[base + 8]) = mx[1];
            *reinterpret_cast<u16x8*>(&tmin[base]) = mn[0];
            *reinterpret_cast<u16x8*>(&tmin[base + 8]) = mn[1];
            __syncthreads();
        }
    } else if (blk < 11) {
        const int layer = blk - 8;
        const float* W = (layer == 0) ? W0 : ((layer == 1) ? W1 : W2);
        const int FRS = (layer == 0) ? 32 : 24;
        const int l = tid & 63;
        for (int fr = tid >> 6; fr < FRS; fr += 8) {
            int kt = fr >> 2, nt = fr & 3;
#pragma unroll
            for (int e = 0; e < 8; ++e) {
                int row = kt * 32 + ((l >> 4) << 3) + e;
                int col = nt * 16 + (l & 15);
                wf[((size_t)(layer * 32 + fr) * 64 + l) * 8 + e] = f2bf(W[row * 64 + col]);
            }
        }
    } else if (blk < 139) {
        const int x = blk - 11;
        const int c = x & 63, b = x >> 6;
        const int t = tid;
        float* smax = reinterpret_cast<float*>(lmax);
        float* smin = reinterpret_cast<float*>(lmin);
        float v = f[((size_t)(b * T_ + t) << 6) + c];
        smax[t] = v; smin[t] = v;
        __syncthreads();
        for (int off = 1; off < 512; off <<= 1) {
            float a = (t + off < 512) ? smax[t + off] : -1e30f;
            float m = (t + off < 512) ? smin[t + off] : 1e30f;
            __syncthreads();
            smax[t] = fmaxf(smax[t], a);
            smin[t] = fminf(smin[t], m);
            __syncthreads();
        }
        cur0bf[((size_t)(b * T_ + t) << 7) + c] = f2bf(smax[t]);
        cur0bf[((size_t)(b * T_ + t) << 7) + 64 + c] = f2bf(smin[t]);
    } else if (blk < 171) {
        const int x = blk - 139;
        const int jt = x & 15, b = x >> 4;
        const int jj = tid >> 4, c8 = tid & 15;
        const bool ismin = c8 >= 8;
        unsigned short (*sc)[128] = reinterpret_cast<unsigned short (*)[128]>(lmax);

        const float* fp = &f[((size_t)(b * T_ + jt * 32 + jj) << 6) + (c8 & 7) * 8];
        u16x8 r;
#pragma unroll
        for (int e = 0; e < 8; ++e) r[e] = f2bf(fp[e]);

#pragma unroll
        for (int off = 1; off < 32; off <<= 1) {
            *reinterpret_cast<u16x8*>(&sc[jj][c8 * 8]) = r;
            __syncthreads();
            if (jj >= off) {
                u16x8 q = *reinterpret_cast<const u16x8*>(&sc[jj - off][c8 * 8]);
#pragma unroll
                for (int e = 0; e < 8; ++e)
                    r[e] = ismin ? minbits(r[e], q[e]) : maxbits(r[e], q[e]);
            }
            __syncthreads();
        }
        *reinterpret_cast<u16x8*>(&intra[((size_t)((b * 16 + jt) * 32 + jj) << 7) + c8 * 8]) = r;
    } else {
        int fi = (blk - 171) * 512 + tid;
        float4 z = {0.f, 0.f, 0.f, 0.f};
        if (fi < 16384)       reinterpret_cast<float4*>(z0)[fi] = z;
        else if (fi < 32768)  reinterpret_cast<float4*>(z1)[fi - 16384] = z;
        else                  reinterpret_cast<float4*>(z2)[fi - 32768] = z;
    }
}

// ---------------------------------------------------------------------------
// Pair GEMM over triangular tiles — ZERO LDS, ZERO barriers.
// Block = (b, 4 i's, 32 j's); wave w owns row i = i0+w.
// Every MFMA A-fragment chunk is loaded directly from global (L2-resident):
//   cur part: 16B from cur0bf (bf16) or 32B+cvt from curprev (fp32)
//   r part:   16B from intra, combined with per-block prefix pv[krt] (regs)
// Diag blocks: per-lane full-range sparse-table queries.
// ---------------------------------------------------------------------------
template <int C, bool FROM_TAB>
__global__ __launch_bounds__(256) void pair_kernel(
    const unsigned short* __restrict__ tabmax,
    const unsigned short* __restrict__ tabmin,
    const unsigned short* __restrict__ cur0bf,  // [B,T,128] bf16
    const unsigned short* __restrict__ intra,   // [B,16,32,128] bf16
    const float* __restrict__ curprev,          // fp32 [B,T,64]; unused if FROM_TAB
    const unsigned short* __restrict__ wf,      // layer base, fragment order
    const float* __restrict__ bias,
    float* __restrict__ out) {

    constexpr int KTC = C / 32;       // 4 or 2
    constexpr int KT = KTC + 4;       // 8 or 6

    int m = blockIdx.x;
    int b = 0;
    if (m >= NBLK_PER_B) { b = 1; m -= NBLK_PER_B; }
    int jt = 0;
    while (m >= 4 * (jt + 1) * (jt + 2)) ++jt;
    const int it = m - 4 * jt * (jt + 1);
    const bool diag = (it >= 8 * jt);
    const int i0 = it * 4, j0 = jt * 32;

    const int tid = threadIdx.x;
    const int l = tid & 63, w = tid >> 6;
    const int lg = l >> 4, li = l & 15;
    const int pi = i0 + w;

    // ---- per-block prefix values pv[krt] (non-diag), or per-s query params (diag) ----
    u16x8 pv[4];
    int kk_s[2], t2_s[2], je_s[2];
    if (!diag) {
        const int len = j0 - pi;               // >= 1
        const int kk = 31 - __clz(len);
        const int t2 = j0 - (1 << kk);
#pragma unroll
        for (int krt = 0; krt < 4; ++krt) {
            const int c8 = krt * 4 + lg;
            const unsigned short* tab = (c8 < 8) ? tabmax : tabmin;
            const int cc = (c8 & 7) * 8;
            u16x8 va = *reinterpret_cast<const u16x8*>(&tab[(((size_t)(kk * B_ + b) * T_ + pi) << 6) + cc]);
            u16x8 vb = *reinterpret_cast<const u16x8*>(&tab[(((size_t)(kk * B_ + b) * T_ + t2) << 6) + cc]);
#pragma unroll
            for (int e = 0; e < 8; ++e)
                pv[krt][e] = (c8 < 8) ? maxbits(va[e], vb[e]) : minbits(va[e], vb[e]);
        }
    } else {
#pragma unroll
        for (int s = 0; s < 2; ++s) {
            const int pj = j0 + 16 * s + li;
            const int je = (pj < pi) ? pi : pj;
            const int len = je - pi + 1;
            kk_s[s] = 31 - __clz(len);
            t2_s[s] = je + 1 - (1 << kk_s[s]);
            je_s[s] = je;
        }
    }

    // ---- GEMM: all operands straight from global ----
    f32x4 acc[2][4];
#pragma unroll
    for (int s = 0; s < 2; ++s)
#pragma unroll
        for (int nt = 0; nt < 4; ++nt) acc[s][nt] = (f32x4){0.f, 0.f, 0.f, 0.f};

#pragma unroll
    for (int kt = 0; kt < KT; ++kt) {
        bf16x8 wfr[4];
#pragma unroll
        for (int nt = 0; nt < 4; ++nt)
            wfr[nt] = *reinterpret_cast<const bf16x8*>(&wf[(size_t)((kt * 4 + nt) * 64 + l) * 8]);

#pragma unroll
        for (int s = 0; s < 2; ++s) {
            const int pjj = 16 * s + li;
            const int pj = j0 + pjj;
            bf16x8 av;
            if (kt < KTC) {
                if (FROM_TAB) {
                    av = *reinterpret_cast<const bf16x8*>(
                        &cur0bf[((size_t)(b * T_ + pj) << 7) + kt * 32 + lg * 8]);
                } else {
                    const float* cp = &curprev[((size_t)(b * T_ + pj) << 6) + kt * 32 + lg * 8];
                    float4 v0 = *reinterpret_cast<const float4*>(cp);
                    float4 v1 = *reinterpret_cast<const float4*>(cp + 4);
                    av[0] = f2bf(v0.x); av[1] = f2bf(v0.y); av[2] = f2bf(v0.z); av[3] = f2bf(v0.w);
                    av[4] = f2bf(v1.x); av[5] = f2bf(v1.y); av[6] = f2bf(v1.z); av[7] = f2bf(v1.w);
                }
            } else {
                const int krt = kt - KTC;
                if (!diag) {
                    u16x8 iv = *reinterpret_cast<const u16x8*>(
                        &intra[((size_t)((b * 16 + jt) * 32 + pjj) << 7) + (krt * 4 + lg) * 8]);
                    if (krt < 2) {
#pragma unroll
                        for (int e = 0; e < 8; ++e) av[e] = (short)maxbits(iv[e], pv[krt][e]);
                    } else {
#pragma unroll
                        for (int e = 0; e < 8; ++e) av[e] = (short)minbits(iv[e], pv[krt][e]);
                    }
                } else {
                    const int c8 = krt * 4 + lg;
                    const unsigned short* tab = (krt < 2) ? tabmax : tabmin;
                    const int cc = (c8 & 7) * 8;
                    const int kk = kk_s[s], t2 = t2_s[s];
                    u16x8 va = *reinterpret_cast<const u16x8*>(&tab[(((size_t)(kk * B_ + b) * T_ + pi) << 6) + cc]);
                    u16x8 vb = *reinterpret_cast<const u16x8*>(&tab[(((size_t)(kk * B_ + b) * T_ + t2) << 6) + cc]);
                    if (krt < 2) {
#pragma unroll
                        for (int e = 0; e < 8; ++e) av[e] = (short)maxbits(va[e], vb[e]);
                    } else {
#pragma unroll
                        for (int e = 0; e < 8; ++e) av[e] = (short)minbits(va[e], vb[e]);
                    }
                }
            }
#pragma unroll
            for (int nt = 0; nt < 4; ++nt)
                acc[s][nt] = __builtin_amdgcn_mfma_f32_16x16x32_bf16(av, wfr[nt], acc[s][nt], 0, 0, 0);
        }
    }

    // ---- epilogue: wave-local max over jj, +bias, sigmoid, atomicMax ----
#pragma unroll
    for (int nt = 0; nt < 4; ++nt) {
        float vm = -1e9f;
#pragma unroll
        for (int s = 0; s < 2; ++s)
#pragma unroll
            for (int r = 0; r < 4; ++r) {
                int jj = 16 * s + lg * 4 + r;
                if (!diag || (j0 + jj >= pi)) vm = fmaxf(vm, acc[s][nt][r]);
            }
        vm = fmaxf(vm, __shfl_xor(vm, 16));
        vm = fmaxf(vm, __shfl_xor(vm, 32));
        if (l < 16) {
            int o = nt * 16 + li;
            float h = 1.0f / (1.0f + __expf(-(vm + bias[o])));
            atomicMax((int*)out + (((size_t)(b * T_ + pi) << 6) + o), __float_as_int(h));
        }
    }
}

// ---------------------------------------------------------------------------
extern "C" void kernel_launch(void* const* d_in, const int* in_sizes, int n_in,
                              void* d_out, int out_size, void* d_ws, size_t ws_size,
                              hipStream_t stream) {
    const float* f  = (const float*)d_in[0];
    const float* W0 = (const float*)d_in[1];
    const float* b0 = (const float*)d_in[2];
    const float* W1 = (const float*)d_in[3];
    const float* b1 = (const float*)d_in[4];
    const float* W2 = (const float*)d_in[5];
    const float* b2 = (const float*)d_in[6];
    float* outp = (float*)d_out;

    // workspace layout
    unsigned short* tabmax = (unsigned short*)d_ws;               // 10*B*T*64
    unsigned short* tabmin = tabmax + 10 * B_ * T_ * 64;          // 10*B*T*64
    unsigned short* wf     = tabmin + 10 * B_ * T_ * 64;          // 3*32*64*8
    unsigned short* cur0bf = wf + 3 * 32 * 64 * 8;                // B*T*128
    unsigned short* intra  = cur0bf + B_ * T_ * 128;              // B*16*32*128
    float* cur1 = (float*)(intra + B_ * 16 * 32 * 128);           // [B,T,64]
    float* cur2 = cur1 + B_ * T_ * 64;                            // [B,T,64]

    prep_kernel<<<dim3(267), dim3(512), 0, stream>>>(f, W0, W1, W2,
                                                     tabmax, tabmin, wf,
                                                     cur0bf, intra,
                                                     cur1, cur2, outp);

    const dim3 pgrid(B_ * NBLK_PER_B);
    pair_kernel<128, true ><<<pgrid, dim3(256), 0, stream>>>(tabmax, tabmin, cur0bf, intra,
                                                             nullptr, wf + 0 * 32 * 64 * 8, b0, cur1);
    pair_kernel<64,  false><<<pgrid, dim3(256), 0, stream>>>(tabmax, tabmin, cur0bf, intra,
                                                             cur1, wf + 1 * 32 * 64 * 8, b1, cur2);
    pair_kernel<64,  false><<<pgrid, dim3(256), 0, stream>>>(tabmax, tabmin, cur0bf, intra,
                                                             cur2, wf + 2 * 32 * 64 * 8, b2, outp);
}

// Round 9
// 102.776 us; speedup vs baseline: 1.2072x; 1.2072x over previous
//
#include <hip/hip_runtime.h>
#include <hip/hip_bf16.h>
#include <math.h>

#define B_ 2
#define T_ 512
#define D_ 64
#define NBLK2_PER_B 576   // sum_{jt2=0..7} (16*jt2+16)

typedef __attribute__((ext_vector_type(8))) short bf16x8;
typedef __attribute__((ext_vector_type(8))) unsigned short u16x8;
typedef __attribute__((ext_vector_type(4))) float f32x4;

static __device__ __forceinline__ unsigned short f2bf(float v) {
    __hip_bfloat16 h = __float2bfloat16(v);
    return *reinterpret_cast<unsigned short*>(&h);
}
static __device__ __forceinline__ float bf2f(unsigned short u) {
    return __uint_as_float(((unsigned)u) << 16);
}
static __device__ __forceinline__ unsigned short maxbits(unsigned short a, unsigned short b) {
    float m = fmaxf(bf2f(a), bf2f(b));
    return (unsigned short)(__float_as_uint(m) >> 16);
}
static __device__ __forceinline__ unsigned short minbits(unsigned short a, unsigned short b) {
    float m = fminf(bf2f(a), bf2f(b));
    return (unsigned short)(__float_as_uint(m) >> 16);
}

// ---------------------------------------------------------------------------
// Fused prep (267 heterogeneous blocks, 512 threads):
//  [0,8)    sparse tables tab[k][b][t][c], k=0..9, bf16
//  [8,11)   W fragment pack (full K)
//  [11,139) cur0bf[b][t][128] = bf16 suffix max/min of f (Hillis-Steele)
//  [139,171) intra[b][jt][jj][128] = running max/min within 32-j tile (scan)
//  [171,267) zero cur1 / cur2 / out
// ---------------------------------------------------------------------------
__global__ __launch_bounds__(512) void prep_kernel(
    const float* __restrict__ f,
    const float* __restrict__ W0, const float* __restrict__ W1, const float* __restrict__ W2,
    unsigned short* __restrict__ tmax, unsigned short* __restrict__ tmin,
    unsigned short* __restrict__ wf,
    unsigned short* __restrict__ cur0bf, unsigned short* __restrict__ intra,
    float* __restrict__ z0, float* __restrict__ z1, float* __restrict__ z2) {

    __shared__ unsigned short lmax[512][16];
    __shared__ unsigned short lmin[512][16];

    const int blk = blockIdx.x;
    const int tid = threadIdx.x;

    if (blk < 8) {
        const int b = blk & 1;
        const int c0 = (blk >> 1) * 16;
        const int t = tid;

        u16x8 mx[2], mn[2];
#pragma unroll
        for (int h = 0; h < 2; ++h) {
            const float* fp = &f[((size_t)(b * T_ + t) << 6) + c0 + h * 8];
#pragma unroll
            for (int e = 0; e < 8; ++e) {
                unsigned short u = f2bf(fp[e]);
                mx[h][e] = u; mn[h][e] = u;
            }
            size_t base = ((size_t)(b * T_ + t) << 6) + c0 + h * 8;
            *reinterpret_cast<u16x8*>(&tmax[base]) = mx[h];
            *reinterpret_cast<u16x8*>(&tmin[base]) = mn[h];
        }
        for (int k = 1; k <= 9; ++k) {
            *reinterpret_cast<u16x8*>(&lmax[t][0]) = mx[0];
            *reinterpret_cast<u16x8*>(&lmax[t][8]) = mx[1];
            *reinterpret_cast<u16x8*>(&lmin[t][0]) = mn[0];
            *reinterpret_cast<u16x8*>(&lmin[t][8]) = mn[1];
            __syncthreads();
            int t2 = t + (1 << (k - 1));
            if (t2 > T_ - 1) t2 = T_ - 1;
            u16x8 qx0 = *reinterpret_cast<const u16x8*>(&lmax[t2][0]);
            u16x8 qx1 = *reinterpret_cast<const u16x8*>(&lmax[t2][8]);
            u16x8 qn0 = *reinterpret_cast<const u16x8*>(&lmin[t2][0]);
            u16x8 qn1 = *reinterpret_cast<const u16x8*>(&lmin[t2][8]);
#pragma unroll
            for (int e = 0; e < 8; ++e) {
                mx[0][e] = maxbits(mx[0][e], qx0[e]);
                mx[1][e] = maxbits(mx[1][e], qx1[e]);
                mn[0][e] = minbits(mn[0][e], qn0[e]);
                mn[1][e] = minbits(mn[1][e], qn1[e]);
            }
            size_t base = ((size_t)((k * B_ + b) * T_ + t) << 6) + c0;
            *reinterpret_cast<u16x8*>(&tmax[base]) = mx[0];
            *reinterpret_cast<u16x8*>(&tmax[base + 8]) = mx[1];
            *reinterpret_cast<u16x8*>(&tmin[base]) = mn[0];
            *reinterpret_cast<u16x8*>(&tmin[base + 8]) = mn[1];
            __syncthreads();
        }
    } else if (blk < 11) {
        const int layer = blk - 8;
        const float* W = (layer == 0) ? W0 : ((layer == 1) ? W1 : W2);
        const int FRS = (layer == 0) ? 32 : 24;
        const int l = tid & 63;
        for (int fr = tid >> 6; fr < FRS; fr += 8) {
            int kt = fr >> 2, nt = fr & 3;
#pragma unroll
            for (int e = 0; e < 8; ++e) {
                int row = kt * 32 + ((l >> 4) << 3) + e;
                int col = nt * 16 + (l & 15);
                wf[((size_t)(layer * 32 + fr) * 64 + l) * 8 + e] = f2bf(W[row * 64 + col]);
            }
        }
    } else if (blk < 139) {
        const int x = blk - 11;
        const int c = x & 63, b = x >> 6;
        const int t = tid;
        float* smax = reinterpret_cast<float*>(lmax);
        float* smin = reinterpret_cast<float*>(lmin);
        float v = f[((size_t)(b * T_ + t) << 6) + c];
        smax[t] = v; smin[t] = v;
        __syncthreads();
        for (int off = 1; off < 512; off <<= 1) {
            float a = (t + off < 512) ? smax[t + off] : -1e30f;
            float m = (t + off < 512) ? smin[t + off] : 1e30f;
            __syncthreads();
            smax[t] = fmaxf(smax[t], a);
            smin[t] = fminf(smin[t], m);
            __syncthreads();
        }
        cur0bf[((size_t)(b * T_ + t) << 7) + c] = f2bf(smax[t]);
        cur0bf[((size_t)(b * T_ + t) << 7) + 64 + c] = f2bf(smin[t]);
    } else if (blk < 171) {
        const int x = blk - 139;
        const int jt = x & 15, b = x >> 4;
        const int jj = tid >> 4, c8 = tid & 15;
        const bool ismin = c8 >= 8;
        unsigned short (*sc)[128] = reinterpret_cast<unsigned short (*)[128]>(lmax);

        const float* fp = &f[((size_t)(b * T_ + jt * 32 + jj) << 6) + (c8 & 7) * 8];
        u16x8 r;
#pragma unroll
        for (int e = 0; e < 8; ++e) r[e] = f2bf(fp[e]);

#pragma unroll
        for (int off = 1; off < 32; off <<= 1) {
            *reinterpret_cast<u16x8*>(&sc[jj][c8 * 8]) = r;
            __syncthreads();
            if (jj >= off) {
                u16x8 q = *reinterpret_cast<const u16x8*>(&sc[jj - off][c8 * 8]);
#pragma unroll
                for (int e = 0; e < 8; ++e)
                    r[e] = ismin ? minbits(r[e], q[e]) : maxbits(r[e], q[e]);
            }
            __syncthreads();
        }
        *reinterpret_cast<u16x8*>(&intra[((size_t)((b * 16 + jt) * 32 + jj) << 7) + c8 * 8]) = r;
    } else {
        int fi = (blk - 171) * 512 + tid;
        float4 z = {0.f, 0.f, 0.f, 0.f};
        if (fi < 16384)       reinterpret_cast<float4*>(z0)[fi] = z;
        else if (fi < 32768)  reinterpret_cast<float4*>(z1)[fi - 16384] = z;
        else                  reinterpret_cast<float4*>(z2)[fi - 32768] = z;
    }
}

// ---------------------------------------------------------------------------
// Pair GEMM over triangular tiles.  Block = (b, 4 i's, 64 j's = two halves).
// One W-fragment register load serves BOTH halves (halves W L1 bandwidth).
// Per half: mode = SKIP (fully below diag) / QUERY (contains diag; per-lane
// table queries) / DECOMP (prefix+intra rank decomposition, LDS staged).
// Wave w owns row i = i0+w; wave-local epilogue, atomicMax to out.
// ---------------------------------------------------------------------------
template <int C, bool FROM_TAB>
__global__ __launch_bounds__(256) void pair_kernel(
    const unsigned short* __restrict__ tabmax,
    const unsigned short* __restrict__ tabmin,
    const unsigned short* __restrict__ cur0bf,  // [B,T,128] bf16
    const unsigned short* __restrict__ intra,   // [B,16,32,128] bf16
    const float* __restrict__ curprev,          // fp32 [B,T,64]; unused if FROM_TAB
    const unsigned short* __restrict__ wf,      // layer base, fragment order
    const float* __restrict__ bias,
    float* __restrict__ out) {

    constexpr int KTC = C / 32;       // 4 or 2
    constexpr int KT = KTC + 4;       // 8 or 6
    constexpr int CP = (C == 128) ? 136 : 72;

    int m = blockIdx.x;
    int b = 0;
    if (m >= NBLK2_PER_B) { b = 1; m -= NBLK2_PER_B; }
    int jt2 = 0;
    while (m >= 8 * (jt2 + 1) * (jt2 + 2)) ++jt2;     // <=7 iters
    const int it = m - 8 * jt2 * (jt2 + 1);           // 0 .. 16*jt2+15
    const int i0 = it * 4, j0 = jt2 * 64;
    const int sub = it - 16 * jt2;                    // >=0 iff diagonal block

    // per-half modes: 0=SKIP, 1=QUERY, 2=DECOMP
    int mode0, mode1;
    if (sub < 0)      { mode0 = 2; mode1 = 2; }
    else if (sub < 8) { mode0 = 1; mode1 = 2; }
    else              { mode0 = 0; mode1 = 1; }
    const int mode[2] = {mode0, mode1};

    const int tid = threadIdx.x;
    const int l = tid & 63, w = tid >> 6;
    const int lg = l >> 4, li = l & 15;
    const int pi = i0 + w;

    __shared__ unsigned short curl[64][CP];
    __shared__ unsigned short intr[64][136];
    __shared__ unsigned short pref[2][4][136];

    // ---- stage cur rows (both halves unless SKIP) ----
    if (FROM_TAB) {
#pragma unroll
        for (int q = 0; q < 4; ++q) {
            int chn = q * 256 + tid;               // 0..1023
            int row = chn >> 4, c8 = chn & 15;
            if (mode[row >> 5] != 0) {
                u16x8 v = *reinterpret_cast<const u16x8*>(
                    &cur0bf[((size_t)(b * T_ + j0 + row) << 7) + c8 * 8]);
                *reinterpret_cast<u16x8*>(&curl[row][c8 * 8]) = v;
            }
        }
    } else {
#pragma unroll
        for (int q = 0; q < 2; ++q) {
            int chn = q * 256 + tid;               // 0..511
            int row = chn >> 3, c8 = chn & 7;
            if (mode[row >> 5] != 0) {
                const float* cp = &curprev[((size_t)(b * T_ + j0 + row) << 6) + c8 * 8];
                float4 v0 = *reinterpret_cast<const float4*>(cp);
                float4 v1 = *reinterpret_cast<const float4*>(cp + 4);
                u16x8 r;
                r[0] = f2bf(v0.x); r[1] = f2bf(v0.y); r[2] = f2bf(v0.z); r[3] = f2bf(v0.w);
                r[4] = f2bf(v1.x); r[5] = f2bf(v1.y); r[6] = f2bf(v1.z); r[7] = f2bf(v1.w);
                *reinterpret_cast<u16x8*>(&curl[row][c8 * 8]) = r;
            }
        }
    }

    // ---- stage intra rows (DECOMP halves) ----
#pragma unroll
    for (int q = 0; q < 4; ++q) {
        int chn = q * 256 + tid;
        int row = chn >> 4, c8 = chn & 15;
        int h = row >> 5;
        if (mode[h] == 2) {
            int jtl = jt2 * 2 + h;
            u16x8 v = *reinterpret_cast<const u16x8*>(
                &intra[((size_t)((b * 16 + jtl) * 32 + (row & 31)) << 7) + c8 * 8]);
            *reinterpret_cast<u16x8*>(&intr[row][c8 * 8]) = v;
        }
    }

    // ---- prefix queries (DECOMP halves): range [i, j0h-1] ----
    if (tid < 128) {
        int h = tid >> 6, isel = (tid >> 4) & 3, c8 = tid & 15;
        if (mode[h] == 2) {
            int i = i0 + isel;
            int j0h = j0 + 32 * h;
            int len = j0h - i;                     // >= 1
            int kk = 31 - __clz(len);
            int t2 = j0h - (1 << kk);
            const unsigned short* tab = (c8 < 8) ? tabmax : tabmin;
            int cc = (c8 & 7) * 8;
            u16x8 va = *reinterpret_cast<const u16x8*>(&tab[(((size_t)(kk * B_ + b) * T_ + i) << 6) + cc]);
            u16x8 vb = *reinterpret_cast<const u16x8*>(&tab[(((size_t)(kk * B_ + b) * T_ + t2) << 6) + cc]);
            u16x8 r;
#pragma unroll
            for (int e = 0; e < 8; ++e)
                r[e] = (c8 < 8) ? maxbits(va[e], vb[e]) : minbits(va[e], vb[e]);
            *reinterpret_cast<u16x8*>(&pref[h][isel][c8 * 8]) = r;
        }
    }
    __syncthreads();

    // ---- per-wave registers: pv for DECOMP halves, query params for QUERY ----
    u16x8 pv[2][4];
    int kk_q[2][2], t2_q[2][2];
#pragma unroll
    for (int h = 0; h < 2; ++h) {
        if (mode[h] == 2) {
#pragma unroll
            for (int krt = 0; krt < 4; ++krt)
                pv[h][krt] = *reinterpret_cast<const u16x8*>(&pref[h][w][(krt * 4 + lg) * 8]);
        } else if (mode[h] == 1) {
#pragma unroll
            for (int s = 0; s < 2; ++s) {
                int pj = j0 + 32 * h + 16 * s + li;
                int je = (pj < pi) ? pi : pj;
                int len = je - pi + 1;
                kk_q[h][s] = 31 - __clz(len);
                t2_q[h][s] = je + 1 - (1 << kk_q[h][s]);
            }
        }
    }

    // ---- GEMM: one W load per kt serves both halves ----
    f32x4 acc[2][2][4];
#pragma unroll
    for (int h = 0; h < 2; ++h)
#pragma unroll
        for (int s = 0; s < 2; ++s)
#pragma unroll
            for (int nt = 0; nt < 4; ++nt) acc[h][s][nt] = (f32x4){0.f, 0.f, 0.f, 0.f};

#pragma unroll
    for (int kt = 0; kt < KT; ++kt) {
        bf16x8 wfr[4];
#pragma unroll
        for (int nt = 0; nt < 4; ++nt)
            wfr[nt] = *reinterpret_cast<const bf16x8*>(&wf[(size_t)((kt * 4 + nt) * 64 + l) * 8]);

#pragma unroll
        for (int h = 0; h < 2; ++h) {
            if (mode[h] == 0) continue;
#pragma unroll
            for (int s = 0; s < 2; ++s) {
                const int pjj = 16 * s + li;
                const int row = 32 * h + pjj;
                bf16x8 av;
                if (kt < KTC) {
                    av = *reinterpret_cast<const bf16x8*>(&curl[row][kt * 32 + lg * 8]);
                } else {
                    const int krt = kt - KTC;
                    if (mode[h] == 2) {
                        u16x8 iv = *reinterpret_cast<const u16x8*>(&intr[row][(krt * 4 + lg) * 8]);
                        if (krt < 2) {
#pragma unroll
                            for (int e = 0; e < 8; ++e) av[e] = (short)maxbits(iv[e], pv[h][krt][e]);
                        } else {
#pragma unroll
                            for (int e = 0; e < 8; ++e) av[e] = (short)minbits(iv[e], pv[h][krt][e]);
                        }
                    } else {
                        const int c8 = krt * 4 + lg;
                        const unsigned short* tab = (krt < 2) ? tabmax : tabmin;
                        const int cc = (c8 & 7) * 8;
                        const int kk = kk_q[h][s], t2 = t2_q[h][s];
                        u16x8 va = *reinterpret_cast<const u16x8*>(&tab[(((size_t)(kk * B_ + b) * T_ + pi) << 6) + cc]);
                        u16x8 vb = *reinterpret_cast<const u16x8*>(&tab[(((size_t)(kk * B_ + b) * T_ + t2) << 6) + cc]);
                        if (krt < 2) {
#pragma unroll
                            for (int e = 0; e < 8; ++e) av[e] = (short)maxbits(va[e], vb[e]);
                        } else {
#pragma unroll
                            for (int e = 0; e < 8; ++e) av[e] = (short)minbits(va[e], vb[e]);
                        }
                    }
                }
#pragma unroll
                for (int nt = 0; nt < 4; ++nt)
                    acc[h][s][nt] = __builtin_amdgcn_mfma_f32_16x16x32_bf16(av, wfr[nt], acc[h][s][nt], 0, 0, 0);
            }
        }
    }

    // ---- epilogue: wave-local max over valid jj, +bias, sigmoid, atomicMax ----
#pragma unroll
    for (int nt = 0; nt < 4; ++nt) {
        float vm = -1e9f;
#pragma unroll
        for (int h = 0; h < 2; ++h) {
            if (mode[h] == 0) continue;
#pragma unroll
            for (int s = 0; s < 2; ++s)
#pragma unroll
                for (int r = 0; r < 4; ++r) {
                    int jj = 32 * h + 16 * s + lg * 4 + r;
                    if (mode[h] == 2 || (j0 + jj >= pi)) vm = fmaxf(vm, acc[h][s][nt][r]);
                }
        }
        vm = fmaxf(vm, __shfl_xor(vm, 16));
        vm = fmaxf(vm, __shfl_xor(vm, 32));
        if (l < 16) {
            int o = nt * 16 + li;
            float hh = 1.0f / (1.0f + __expf(-(vm + bias[o])));
            atomicMax((int*)out + (((size_t)(b * T_ + pi) << 6) + o), __float_as_int(hh));
        }
    }
}

// ---------------------------------------------------------------------------
extern "C" void kernel_launch(void* const* d_in, const int* in_sizes, int n_in,
                              void* d_out, int out_size, void* d_ws, size_t ws_size,
                              hipStream_t stream) {
    const float* f  = (const float*)d_in[0];
    const float* W0 = (const float*)d_in[1];
    const float* b0 = (const float*)d_in[2];
    const float* W1 = (const float*)d_in[3];
    const float* b1 = (const float*)d_in[4];
    const float* W2 = (const float*)d_in[5];
    const float* b2 = (const float*)d_in[6];
    float* outp = (float*)d_out;

    // workspace layout
    unsigned short* tabmax = (unsigned short*)d_ws;               // 10*B*T*64
    unsigned short* tabmin = tabmax + 10 * B_ * T_ * 64;          // 10*B*T*64
    unsigned short* wf     = tabmin + 10 * B_ * T_ * 64;          // 3*32*64*8
    unsigned short* cur0bf = wf + 3 * 32 * 64 * 8;                // B*T*128
    unsigned short* intra  = cur0bf + B_ * T_ * 128;              // B*16*32*128
    float* cur1 = (float*)(intra + B_ * 16 * 32 * 128);           // [B,T,64]
    float* cur2 = cur1 + B_ * T_ * 64;                            // [B,T,64]

    prep_kernel<<<dim3(267), dim3(512), 0, stream>>>(f, W0, W1, W2,
                                                     tabmax, tabmin, wf,
                                                     cur0bf, intra,
                                                     cur1, cur2, outp);

    const dim3 pgrid(B_ * NBLK2_PER_B);
    pair_kernel<128, true ><<<pgrid, dim3(256), 0, stream>>>(tabmax, tabmin, cur0bf, intra,
                                                             nullptr, wf + 0 * 32 * 64 * 8, b0, cur1);
    pair_kernel<64,  false><<<pgrid, dim3(256), 0, stream>>>(tabmax, tabmin, cur0bf, intra,
                                                             cur1, wf + 1 * 32 * 64 * 8, b1, cur2);
    pair_kernel<64,  false><<<pgrid, dim3(256), 0, stream>>>(tabmax, tabmin, cur0bf, intra,
                                                             cur2, wf + 2 * 32 * 64 * 8, b2, outp);
}

// Round 10
// 93.936 us; speedup vs baseline: 1.3208x; 1.0941x over previous
//
#include <hip/hip_runtime.h>
#include <hip/hip_bf16.h>
#include <math.h>

#define B_ 2
#define T_ 512
#define D_ 64
#define NBLK8_PER_B 544   // sum_{jt=0..15} (4*jt+4)

typedef __attribute__((ext_vector_type(8))) short bf16x8;
typedef __attribute__((ext_vector_type(8))) unsigned short u16x8;
typedef __attribute__((ext_vector_type(4))) float f32x4;

static __device__ __forceinline__ unsigned short f2bf(float v) {
    __hip_bfloat16 h = __float2bfloat16(v);
    return *reinterpret_cast<unsigned short*>(&h);
}
static __device__ __forceinline__ float bf2f(unsigned short u) {
    return __uint_as_float(((unsigned)u) << 16);
}
static __device__ __forceinline__ unsigned short maxbits(unsigned short a, unsigned short b) {
    float m = fmaxf(bf2f(a), bf2f(b));
    return (unsigned short)(__float_as_uint(m) >> 16);
}
static __device__ __forceinline__ unsigned short minbits(unsigned short a, unsigned short b) {
    float m = fminf(bf2f(a), bf2f(b));
    return (unsigned short)(__float_as_uint(m) >> 16);
}

// ---------------------------------------------------------------------------
// Fused prep (267 heterogeneous blocks, 512 threads):
//  [0,8)    sparse tables tab[k][b][t][c], k=0..9, bf16
//  [8,11)   W fragment pack (full K)
//  [11,139) cur0bf[b][t][128] = bf16 suffix max/min of f (Hillis-Steele)
//  [139,171) intra[b][jt][jj][128] = running max/min within 32-j tile (scan)
//  [171,267) zero cur1 / cur2 / out
// ---------------------------------------------------------------------------
__global__ __launch_bounds__(512) void prep_kernel(
    const float* __restrict__ f,
    const float* __restrict__ W0, const float* __restrict__ W1, const float* __restrict__ W2,
    unsigned short* __restrict__ tmax, unsigned short* __restrict__ tmin,
    unsigned short* __restrict__ wf,
    unsigned short* __restrict__ cur0bf, unsigned short* __restrict__ intra,
    float* __restrict__ z0, float* __restrict__ z1, float* __restrict__ z2) {

    __shared__ unsigned short lmax[512][16];
    __shared__ unsigned short lmin[512][16];

    const int blk = blockIdx.x;
    const int tid = threadIdx.x;

    if (blk < 8) {
        const int b = blk & 1;
        const int c0 = (blk >> 1) * 16;
        const int t = tid;

        u16x8 mx[2], mn[2];
#pragma unroll
        for (int h = 0; h < 2; ++h) {
            const float* fp = &f[((size_t)(b * T_ + t) << 6) + c0 + h * 8];
#pragma unroll
            for (int e = 0; e < 8; ++e) {
                unsigned short u = f2bf(fp[e]);
                mx[h][e] = u; mn[h][e] = u;
            }
            size_t base = ((size_t)(b * T_ + t) << 6) + c0 + h * 8;
            *reinterpret_cast<u16x8*>(&tmax[base]) = mx[h];
            *reinterpret_cast<u16x8*>(&tmin[base]) = mn[h];
        }
        for (int k = 1; k <= 9; ++k) {
            *reinterpret_cast<u16x8*>(&lmax[t][0]) = mx[0];
            *reinterpret_cast<u16x8*>(&lmax[t][8]) = mx[1];
            *reinterpret_cast<u16x8*>(&lmin[t][0]) = mn[0];
            *reinterpret_cast<u16x8*>(&lmin[t][8]) = mn[1];
            __syncthreads();
            int t2 = t + (1 << (k - 1));
            if (t2 > T_ - 1) t2 = T_ - 1;
            u16x8 qx0 = *reinterpret_cast<const u16x8*>(&lmax[t2][0]);
            u16x8 qx1 = *reinterpret_cast<const u16x8*>(&lmax[t2][8]);
            u16x8 qn0 = *reinterpret_cast<const u16x8*>(&lmin[t2][0]);
            u16x8 qn1 = *reinterpret_cast<const u16x8*>(&lmin[t2][8]);
#pragma unroll
            for (int e = 0; e < 8; ++e) {
                mx[0][e] = maxbits(mx[0][e], qx0[e]);
                mx[1][e] = maxbits(mx[1][e], qx1[e]);
                mn[0][e] = minbits(mn[0][e], qn0[e]);
                mn[1][e] = minbits(mn[1][e], qn1[e]);
            }
            size_t base = ((size_t)((k * B_ + b) * T_ + t) << 6) + c0;
            *reinterpret_cast<u16x8*>(&tmax[base]) = mx[0];
            *reinterpret_cast<u16x8*>(&tmax[base + 8]) = mx[1];
            *reinterpret_cast<u16x8*>(&tmin[base]) = mn[0];
            *reinterpret_cast<u16x8*>(&tmin[base + 8]) = mn[1];
            __syncthreads();
        }
    } else if (blk < 11) {
        const int layer = blk - 8;
        const float* W = (layer == 0) ? W0 : ((layer == 1) ? W1 : W2);
        const int FRS = (layer == 0) ? 32 : 24;
        const int l = tid & 63;
        for (int fr = tid >> 6; fr < FRS; fr += 8) {
            int kt = fr >> 2, nt = fr & 3;
#pragma unroll
            for (int e = 0; e < 8; ++e) {
                int row = kt * 32 + ((l >> 4) << 3) + e;
                int col = nt * 16 + (l & 15);
                wf[((size_t)(layer * 32 + fr) * 64 + l) * 8 + e] = f2bf(W[row * 64 + col]);
            }
        }
    } else if (blk < 139) {
        const int x = blk - 11;
        const int c = x & 63, b = x >> 6;
        const int t = tid;
        float* smax = reinterpret_cast<float*>(lmax);
        float* smin = reinterpret_cast<float*>(lmin);
        float v = f[((size_t)(b * T_ + t) << 6) + c];
        smax[t] = v; smin[t] = v;
        __syncthreads();
        for (int off = 1; off < 512; off <<= 1) {
            float a = (t + off < 512) ? smax[t + off] : -1e30f;
            float m = (t + off < 512) ? smin[t + off] : 1e30f;
            __syncthreads();
            smax[t] = fmaxf(smax[t], a);
            smin[t] = fminf(smin[t], m);
            __syncthreads();
        }
        cur0bf[((size_t)(b * T_ + t) << 7) + c] = f2bf(smax[t]);
        cur0bf[((size_t)(b * T_ + t) << 7) + 64 + c] = f2bf(smin[t]);
    } else if (blk < 171) {
        const int x = blk - 139;
        const int jt = x & 15, b = x >> 4;
        const int jj = tid >> 4, c8 = tid & 15;
        const bool ismin = c8 >= 8;
        unsigned short (*sc)[128] = reinterpret_cast<unsigned short (*)[128]>(lmax);

        const float* fp = &f[((size_t)(b * T_ + jt * 32 + jj) << 6) + (c8 & 7) * 8];
        u16x8 r;
#pragma unroll
        for (int e = 0; e < 8; ++e) r[e] = f2bf(fp[e]);

#pragma unroll
        for (int off = 1; off < 32; off <<= 1) {
            *reinterpret_cast<u16x8*>(&sc[jj][c8 * 8]) = r;
            __syncthreads();
            if (jj >= off) {
                u16x8 q = *reinterpret_cast<const u16x8*>(&sc[jj - off][c8 * 8]);
#pragma unroll
                for (int e = 0; e < 8; ++e)
                    r[e] = ismin ? minbits(r[e], q[e]) : maxbits(r[e], q[e]);
            }
            __syncthreads();
        }
        *reinterpret_cast<u16x8*>(&intra[((size_t)((b * 16 + jt) * 32 + jj) << 7) + c8 * 8]) = r;
    } else {
        int fi = (blk - 171) * 512 + tid;
        float4 z = {0.f, 0.f, 0.f, 0.f};
        if (fi < 16384)       reinterpret_cast<float4*>(z0)[fi] = z;
        else if (fi < 32768)  reinterpret_cast<float4*>(z1)[fi - 16384] = z;
        else                  reinterpret_cast<float4*>(z2)[fi - 32768] = z;
    }
}

// ---------------------------------------------------------------------------
// Pair GEMM over triangular tiles.  Block = (b, 8 i's, 32 j's); wave w owns
// rows piA = i0+w and piB = i0+4+w.  The A-matrix cur-part is i-independent:
// its MFMAs are computed once (accA), then the accumulator is forked
// (accB = accA) and only the r-phase (prefix-combine, per-i) is done twice.
// W fragment loads and intr ds_reads are shared between the two i-rows.
// Diag blocks (it >= 4*jt): per-lane sparse-table queries per i.
// ---------------------------------------------------------------------------
template <int C, bool FROM_TAB>
__global__ __launch_bounds__(256, 4) void pair_kernel(
    const unsigned short* __restrict__ tabmax,
    const unsigned short* __restrict__ tabmin,
    const unsigned short* __restrict__ cur0bf,  // [B,T,128] bf16
    const unsigned short* __restrict__ intra,   // [B,16,32,128] bf16
    const float* __restrict__ curprev,          // fp32 [B,T,64]; unused if FROM_TAB
    const unsigned short* __restrict__ wf,      // layer base, fragment order
    const float* __restrict__ bias,
    float* __restrict__ out) {

    constexpr int KTC = C / 32;       // 4 or 2
    constexpr int CP = (C == 128) ? 136 : 72;

    int m = blockIdx.x;
    int b = 0;
    if (m >= NBLK8_PER_B) { b = 1; m -= NBLK8_PER_B; }
    int jt = 0;
    while (m >= 2 * (jt + 1) * (jt + 2)) ++jt;        // <=15 iters
    const int it = m - 2 * jt * (jt + 1);             // 0 .. 4*jt+3
    const bool diag = (it >= 4 * jt);
    const int i0 = it * 8, j0 = jt * 32;

    const int tid = threadIdx.x;
    const int l = tid & 63, w = tid >> 6;
    const int lg = l >> 4, li = l & 15;
    const int piA = i0 + w, piB = i0 + 4 + w;

    __shared__ unsigned short curl[32][CP];
    __shared__ unsigned short intr[32][136];
    __shared__ unsigned short pref[8][136];

    // ---- stage cur tile [32 j][C ch] as bf16 ----
    if (FROM_TAB) {
#pragma unroll
        for (int q = 0; q < 2; ++q) {
            int chn = q * 256 + tid;
            int jj = chn >> 4, c8 = chn & 15;
            u16x8 v = *reinterpret_cast<const u16x8*>(
                &cur0bf[((size_t)(b * T_ + j0 + jj) << 7) + c8 * 8]);
            *reinterpret_cast<u16x8*>(&curl[jj][c8 * 8]) = v;
        }
    } else {
        int jj = tid >> 3, c8 = tid & 7;
        const float* cp = &curprev[((size_t)(b * T_ + j0 + jj) << 6) + c8 * 8];
        float4 v0 = *reinterpret_cast<const float4*>(cp);
        float4 v1 = *reinterpret_cast<const float4*>(cp + 4);
        u16x8 r;
        r[0] = f2bf(v0.x); r[1] = f2bf(v0.y); r[2] = f2bf(v0.z); r[3] = f2bf(v0.w);
        r[4] = f2bf(v1.x); r[5] = f2bf(v1.y); r[6] = f2bf(v1.z); r[7] = f2bf(v1.w);
        *reinterpret_cast<u16x8*>(&curl[jj][c8 * 8]) = r;
    }

    if (!diag) {
        // ---- intra tile: contiguous copy ----
#pragma unroll
        for (int q = 0; q < 2; ++q) {
            int chn = q * 256 + tid;
            int jj = chn >> 4, c8 = chn & 15;
            u16x8 v = *reinterpret_cast<const u16x8*>(
                &intra[((size_t)((b * 16 + jt) * 32 + jj) << 7) + c8 * 8]);
            *reinterpret_cast<u16x8*>(&intr[jj][c8 * 8]) = v;
        }
        // ---- prefix queries: 8 i's x 16 chunks, range [i, j0-1] ----
        if (tid < 128) {
            int isel = tid >> 4, c8 = tid & 15;
            int i = i0 + isel;
            int len = j0 - i;                  // >= 1 (non-diag)
            int kk = 31 - __clz(len);
            int t2 = j0 - (1 << kk);
            const unsigned short* tab = (c8 < 8) ? tabmax : tabmin;
            int cc = (c8 & 7) * 8;
            u16x8 va = *reinterpret_cast<const u16x8*>(&tab[(((size_t)(kk * B_ + b) * T_ + i) << 6) + cc]);
            u16x8 vb = *reinterpret_cast<const u16x8*>(&tab[(((size_t)(kk * B_ + b) * T_ + t2) << 6) + cc]);
            u16x8 r;
#pragma unroll
            for (int e = 0; e < 8; ++e)
                r[e] = (c8 < 8) ? maxbits(va[e], vb[e]) : minbits(va[e], vb[e]);
            *reinterpret_cast<u16x8*>(&pref[isel][c8 * 8]) = r;
        }
    }
    __syncthreads();

    // ---- diag query params (per i, per s) ----
    int kkA[2], t2A[2], kkB[2], t2B[2];
    if (diag) {
#pragma unroll
        for (int s = 0; s < 2; ++s) {
            int pj = j0 + 16 * s + li;
            int jeA = (pj < piA) ? piA : pj;
            int lenA = jeA - piA + 1;
            kkA[s] = 31 - __clz(lenA);
            t2A[s] = jeA + 1 - (1 << kkA[s]);
            int jeB = (pj < piB) ? piB : pj;
            int lenB = jeB - piB + 1;
            kkB[s] = 31 - __clz(lenB);
            t2B[s] = jeB + 1 - (1 << kkB[s]);
        }
    }

    // ---- cur phase (shared between the two i-rows) ----
    f32x4 accA[2][4];
#pragma unroll
    for (int s = 0; s < 2; ++s)
#pragma unroll
        for (int nt = 0; nt < 4; ++nt) accA[s][nt] = (f32x4){0.f, 0.f, 0.f, 0.f};

#pragma unroll
    for (int kt = 0; kt < KTC; ++kt) {
        bf16x8 wfr[4];
#pragma unroll
        for (int nt = 0; nt < 4; ++nt)
            wfr[nt] = *reinterpret_cast<const bf16x8*>(&wf[(size_t)((kt * 4 + nt) * 64 + l) * 8]);
#pragma unroll
        for (int s = 0; s < 2; ++s) {
            bf16x8 av = *reinterpret_cast<const bf16x8*>(&curl[16 * s + li][kt * 32 + lg * 8]);
#pragma unroll
            for (int nt = 0; nt < 4; ++nt)
                accA[s][nt] = __builtin_amdgcn_mfma_f32_16x16x32_bf16(av, wfr[nt], accA[s][nt], 0, 0, 0);
        }
    }

    // ---- fork accumulator ----
    f32x4 accB[2][4];
#pragma unroll
    for (int s = 0; s < 2; ++s)
#pragma unroll
        for (int nt = 0; nt < 4; ++nt) accB[s][nt] = accA[s][nt];

    // ---- r phase: shared W + shared intr ds_read, per-i combine ----
#pragma unroll
    for (int krt = 0; krt < 4; ++krt) {
        bf16x8 wfr[4];
#pragma unroll
        for (int nt = 0; nt < 4; ++nt)
            wfr[nt] = *reinterpret_cast<const bf16x8*>(&wf[(size_t)(((KTC + krt) * 4 + nt) * 64 + l) * 8]);

        u16x8 pvA, pvB;
        if (!diag) {
            pvA = *reinterpret_cast<const u16x8*>(&pref[w][(krt * 4 + lg) * 8]);
            pvB = *reinterpret_cast<const u16x8*>(&pref[w + 4][(krt * 4 + lg) * 8]);
        }

#pragma unroll
        for (int s = 0; s < 2; ++s) {
            bf16x8 avA, avB;
            if (!diag) {
                u16x8 iv = *reinterpret_cast<const u16x8*>(&intr[16 * s + li][(krt * 4 + lg) * 8]);
                if (krt < 2) {
#pragma unroll
                    for (int e = 0; e < 8; ++e) {
                        avA[e] = (short)maxbits(iv[e], pvA[e]);
                        avB[e] = (short)maxbits(iv[e], pvB[e]);
                    }
                } else {
#pragma unroll
                    for (int e = 0; e < 8; ++e) {
                        avA[e] = (short)minbits(iv[e], pvA[e]);
                        avB[e] = (short)minbits(iv[e], pvB[e]);
                    }
                }
            } else {
                const int c8 = krt * 4 + lg;
                const unsigned short* tab = (krt < 2) ? tabmax : tabmin;
                const int cc = (c8 & 7) * 8;
                u16x8 vaA = *reinterpret_cast<const u16x8*>(&tab[(((size_t)(kkA[s] * B_ + b) * T_ + piA) << 6) + cc]);
                u16x8 vbA = *reinterpret_cast<const u16x8*>(&tab[(((size_t)(kkA[s] * B_ + b) * T_ + t2A[s]) << 6) + cc]);
                u16x8 vaB = *reinterpret_cast<const u16x8*>(&tab[(((size_t)(kkB[s] * B_ + b) * T_ + piB) << 6) + cc]);
                u16x8 vbB = *reinterpret_cast<const u16x8*>(&tab[(((size_t)(kkB[s] * B_ + b) * T_ + t2B[s]) << 6) + cc]);
                if (krt < 2) {
#pragma unroll
                    for (int e = 0; e < 8; ++e) {
                        avA[e] = (short)maxbits(vaA[e], vbA[e]);
                        avB[e] = (short)maxbits(vaB[e], vbB[e]);
                    }
                } else {
#pragma unroll
                    for (int e = 0; e < 8; ++e) {
                        avA[e] = (short)minbits(vaA[e], vbA[e]);
                        avB[e] = (short)minbits(vaB[e], vbB[e]);
                    }
                }
            }
#pragma unroll
            for (int nt = 0; nt < 4; ++nt) {
                accA[s][nt] = __builtin_amdgcn_mfma_f32_16x16x32_bf16(avA, wfr[nt], accA[s][nt], 0, 0, 0);
                accB[s][nt] = __builtin_amdgcn_mfma_f32_16x16x32_bf16(avB, wfr[nt], accB[s][nt], 0, 0, 0);
            }
        }
    }

    // ---- epilogue: per-i wave-local max, +bias, sigmoid, atomicMax ----
#pragma unroll
    for (int nt = 0; nt < 4; ++nt) {
        float vmA = -1e9f, vmB = -1e9f;
#pragma unroll
        for (int s = 0; s < 2; ++s)
#pragma unroll
            for (int r = 0; r < 4; ++r) {
                int jj = 16 * s + lg * 4 + r;
                if (!diag || (j0 + jj >= piA)) vmA = fmaxf(vmA, accA[s][nt][r]);
                if (!diag || (j0 + jj >= piB)) vmB = fmaxf(vmB, accB[s][nt][r]);
            }
        vmA = fmaxf(vmA, __shfl_xor(vmA, 16));
        vmA = fmaxf(vmA, __shfl_xor(vmA, 32));
        vmB = fmaxf(vmB, __shfl_xor(vmB, 16));
        vmB = fmaxf(vmB, __shfl_xor(vmB, 32));
        if (l < 16) {
            int o = nt * 16 + li;
            float bo = bias[o];
            float hA = 1.0f / (1.0f + __expf(-(vmA + bo)));
            float hB = 1.0f / (1.0f + __expf(-(vmB + bo)));
            atomicMax((int*)out + (((size_t)(b * T_ + piA) << 6) + o), __float_as_int(hA));
            atomicMax((int*)out + (((size_t)(b * T_ + piB) << 6) + o), __float_as_int(hB));
        }
    }
}

// ---------------------------------------------------------------------------
extern "C" void kernel_launch(void* const* d_in, const int* in_sizes, int n_in,
                              void* d_out, int out_size, void* d_ws, size_t ws_size,
                              hipStream_t stream) {
    const float* f  = (const float*)d_in[0];
    const float* W0 = (const float*)d_in[1];
    const float* b0 = (const float*)d_in[2];
    const float* W1 = (const float*)d_in[3];
    const float* b1 = (const float*)d_in[4];
    const float* W2 = (const float*)d_in[5];
    const float* b2 = (const float*)d_in[6];
    float* outp = (float*)d_out;

    // workspace layout
    unsigned short* tabmax = (unsigned short*)d_ws;               // 10*B*T*64
    unsigned short* tabmin = tabmax + 10 * B_ * T_ * 64;          // 10*B*T*64
    unsigned short* wf     = tabmin + 10 * B_ * T_ * 64;          // 3*32*64*8
    unsigned short* cur0bf = wf + 3 * 32 * 64 * 8;                // B*T*128
    unsigned short* intra  = cur0bf + B_ * T_ * 128;              // B*16*32*128
    float* cur1 = (float*)(intra + B_ * 16 * 32 * 128);           // [B,T,64]
    float* cur2 = cur1 + B_ * T_ * 64;                            // [B,T,64]

    prep_kernel<<<dim3(267), dim3(512), 0, stream>>>(f, W0, W1, W2,
                                                     tabmax, tabmin, wf,
                                                     cur0bf, intra,
                                                     cur1, cur2, outp);

    const dim3 pgrid(B_ * NBLK8_PER_B);
    pair_kernel<128, true ><<<pgrid, dim3(256), 0, stream>>>(tabmax, tabmin, cur0bf, intra,
                                                             nullptr, wf + 0 * 32 * 64 * 8, b0, cur1);
    pair_kernel<64,  false><<<pgrid, dim3(256), 0, stream>>>(tabmax, tabmin, cur0bf, intra,
                                                             cur1, wf + 1 * 32 * 64 * 8, b1, cur2);
    pair_kernel<64,  false><<<pgrid, dim3(256), 0, stream>>>(tabmax, tabmin, cur0bf, intra,
                                                             cur2, wf + 2 * 32 * 64 * 8, b2, outp);
}

// Round 11
// 80.574 us; speedup vs baseline: 1.5399x; 1.1658x over previous
//
#include <hip/hip_runtime.h>
#include <hip/hip_bf16.h>
#include <math.h>

#define B_ 2
#define T_ 512
#define D_ 64
#define NBLK_PER_B 1088   // 128 diag + 960 non-diag

typedef __attribute__((ext_vector_type(8))) short bf16x8;
typedef __attribute__((ext_vector_type(8))) unsigned short u16x8;
typedef __attribute__((ext_vector_type(4))) float f32x4;

static __device__ __forceinline__ unsigned short f2bf(float v) {
    __hip_bfloat16 h = __float2bfloat16(v);
    return *reinterpret_cast<unsigned short*>(&h);
}
static __device__ __forceinline__ float bf2f(unsigned short u) {
    return __uint_as_float(((unsigned)u) << 16);
}
static __device__ __forceinline__ unsigned short maxbits(unsigned short a, unsigned short b) {
    float m = fmaxf(bf2f(a), bf2f(b));
    return (unsigned short)(__float_as_uint(m) >> 16);
}
static __device__ __forceinline__ unsigned short minbits(unsigned short a, unsigned short b) {
    float m = fminf(bf2f(a), bf2f(b));
    return (unsigned short)(__float_as_uint(m) >> 16);
}

// ---------------------------------------------------------------------------
// Fused prep (267 heterogeneous blocks, 512 threads):
//  [0,8)    sparse tables tab[k][b][t][c], k=0..9, bf16
//  [8,11)   W fragment pack (full K)
//  [11,139) cur0bf[b][t][128] = bf16 suffix max/min of f (Hillis-Steele)
//  [139,171) intra[b][jt][jj][128] = running max/min within 32-j tile (scan)
//  [171,267) zero cur1 / cur2 / out
// ---------------------------------------------------------------------------
__global__ __launch_bounds__(512) void prep_kernel(
    const float* __restrict__ f,
    const float* __restrict__ W0, const float* __restrict__ W1, const float* __restrict__ W2,
    unsigned short* __restrict__ tmax, unsigned short* __restrict__ tmin,
    unsigned short* __restrict__ wf,
    unsigned short* __restrict__ cur0bf, unsigned short* __restrict__ intra,
    float* __restrict__ z0, float* __restrict__ z1, float* __restrict__ z2) {

    __shared__ unsigned short lmax[512][16];
    __shared__ unsigned short lmin[512][16];

    const int blk = blockIdx.x;
    const int tid = threadIdx.x;

    if (blk < 8) {
        const int b = blk & 1;
        const int c0 = (blk >> 1) * 16;
        const int t = tid;

        u16x8 mx[2], mn[2];
#pragma unroll
        for (int h = 0; h < 2; ++h) {
            const float* fp = &f[((size_t)(b * T_ + t) << 6) + c0 + h * 8];
#pragma unroll
            for (int e = 0; e < 8; ++e) {
                unsigned short u = f2bf(fp[e]);
                mx[h][e] = u; mn[h][e] = u;
            }
            size_t base = ((size_t)(b * T_ + t) << 6) + c0 + h * 8;
            *reinterpret_cast<u16x8*>(&tmax[base]) = mx[h];
            *reinterpret_cast<u16x8*>(&tmin[base]) = mn[h];
        }
        for (int k = 1; k <= 9; ++k) {
            *reinterpret_cast<u16x8*>(&lmax[t][0]) = mx[0];
            *reinterpret_cast<u16x8*>(&lmax[t][8]) = mx[1];
            *reinterpret_cast<u16x8*>(&lmin[t][0]) = mn[0];
            *reinterpret_cast<u16x8*>(&lmin[t][8]) = mn[1];
            __syncthreads();
            int t2 = t + (1 << (k - 1));
            if (t2 > T_ - 1) t2 = T_ - 1;
            u16x8 qx0 = *reinterpret_cast<const u16x8*>(&lmax[t2][0]);
            u16x8 qx1 = *reinterpret_cast<const u16x8*>(&lmax[t2][8]);
            u16x8 qn0 = *reinterpret_cast<const u16x8*>(&lmin[t2][0]);
            u16x8 qn1 = *reinterpret_cast<const u16x8*>(&lmin[t2][8]);
#pragma unroll
            for (int e = 0; e < 8; ++e) {
                mx[0][e] = maxbits(mx[0][e], qx0[e]);
                mx[1][e] = maxbits(mx[1][e], qx1[e]);
                mn[0][e] = minbits(mn[0][e], qn0[e]);
                mn[1][e] = minbits(mn[1][e], qn1[e]);
            }
            size_t base = ((size_t)((k * B_ + b) * T_ + t) << 6) + c0;
            *reinterpret_cast<u16x8*>(&tmax[base]) = mx[0];
            *reinterpret_cast<u16x8*>(&tmax[base + 8]) = mx[1];
            *reinterpret_cast<u16x8*>(&tmin[base]) = mn[0];
            *reinterpret_cast<u16x8*>(&tmin[base + 8]) = mn[1];
            __syncthreads();
        }
    } else if (blk < 11) {
        const int layer = blk - 8;
        const float* W = (layer == 0) ? W0 : ((layer == 1) ? W1 : W2);
        const int FRS = (layer == 0) ? 32 : 24;
        const int l = tid & 63;
        for (int fr = tid >> 6; fr < FRS; fr += 8) {
            int kt = fr >> 2, nt = fr & 3;
#pragma unroll
            for (int e = 0; e < 8; ++e) {
                int row = kt * 32 + ((l >> 4) << 3) + e;
                int col = nt * 16 + (l & 15);
                wf[((size_t)(layer * 32 + fr) * 64 + l) * 8 + e] = f2bf(W[row * 64 + col]);
            }
        }
    } else if (blk < 139) {
        const int x = blk - 11;
        const int c = x & 63, b = x >> 6;
        const int t = tid;
        float* smax = reinterpret_cast<float*>(lmax);
        float* smin = reinterpret_cast<float*>(lmin);
        float v = f[((size_t)(b * T_ + t) << 6) + c];
        smax[t] = v; smin[t] = v;
        __syncthreads();
        for (int off = 1; off < 512; off <<= 1) {
            float a = (t + off < 512) ? smax[t + off] : -1e30f;
            float m = (t + off < 512) ? smin[t + off] : 1e30f;
            __syncthreads();
            smax[t] = fmaxf(smax[t], a);
            smin[t] = fminf(smin[t], m);
            __syncthreads();
        }
        cur0bf[((size_t)(b * T_ + t) << 7) + c] = f2bf(smax[t]);
        cur0bf[((size_t)(b * T_ + t) << 7) + 64 + c] = f2bf(smin[t]);
    } else if (blk < 171) {
        const int x = blk - 139;
        const int jt = x & 15, b = x >> 4;
        const int jj = tid >> 4, c8 = tid & 15;
        const bool ismin = c8 >= 8;
        unsigned short (*sc)[128] = reinterpret_cast<unsigned short (*)[128]>(lmax);

        const float* fp = &f[((size_t)(b * T_ + jt * 32 + jj) << 6) + (c8 & 7) * 8];
        u16x8 r;
#pragma unroll
        for (int e = 0; e < 8; ++e) r[e] = f2bf(fp[e]);

#pragma unroll
        for (int off = 1; off < 32; off <<= 1) {
            *reinterpret_cast<u16x8*>(&sc[jj][c8 * 8]) = r;
            __syncthreads();
            if (jj >= off) {
                u16x8 q = *reinterpret_cast<const u16x8*>(&sc[jj - off][c8 * 8]);
#pragma unroll
                for (int e = 0; e < 8; ++e)
                    r[e] = ismin ? minbits(r[e], q[e]) : maxbits(r[e], q[e]);
            }
            __syncthreads();
        }
        *reinterpret_cast<u16x8*>(&intra[((size_t)((b * 16 + jt) * 32 + jj) << 7) + c8 * 8]) = r;
    } else {
        int fi = (blk - 171) * 512 + tid;
        float4 z = {0.f, 0.f, 0.f, 0.f};
        if (fi < 16384)       reinterpret_cast<float4*>(z0)[fi] = z;
        else if (fi < 32768)  reinterpret_cast<float4*>(z1)[fi - 16384] = z;
        else                  reinterpret_cast<float4*>(z2)[fi - 32768] = z;
    }
}

// ---------------------------------------------------------------------------
// Pair GEMM over triangular tiles (R6 structure + W-in-LDS + diag-first).
// Block = (b, 4 i's, 32 j's); wave w owns row i = i0+w.  W fragments are
// staged once per block into LDS (contiguous) and read via ds_read_b128 —
// removes the dominant per-block L1/L2 W stream.  Diag blocks ordered first.
// ---------------------------------------------------------------------------
template <int C, bool FROM_TAB>
__global__ __launch_bounds__(256) void pair_kernel(
    const unsigned short* __restrict__ tabmax,
    const unsigned short* __restrict__ tabmin,
    const unsigned short* __restrict__ cur0bf,  // [B,T,128] bf16
    const unsigned short* __restrict__ intra,   // [B,16,32,128] bf16
    const float* __restrict__ curprev,          // fp32 [B,T,64]; unused if FROM_TAB
    const unsigned short* __restrict__ wf,      // layer base, fragment order
    const float* __restrict__ bias,
    float* __restrict__ out) {

    constexpr int KTC = C / 32;       // 4 or 2
    constexpr int KT = KTC + 4;       // 8 or 6
    constexpr int CP = (C == 128) ? 136 : 72;

    // ---- decode: diag blocks first (m < 128), then non-diag ----
    int m = blockIdx.x;
    int b = 0;
    if (m >= NBLK_PER_B) { b = 1; m -= NBLK_PER_B; }
    int jt, it;
    bool diag;
    if (m < 128) {
        diag = true;
        jt = m >> 3;
        it = 8 * jt + (m & 7);
    } else {
        diag = false;
        int m2 = m - 128;
        jt = 1;
        while (m2 >= 4 * jt * (jt + 1)) ++jt;     // <=14 iters
        it = m2 - 4 * jt * (jt - 1);              // 0 .. 8*jt-1
    }
    const int i0 = it * 4, j0 = jt * 32;

    const int tid = threadIdx.x;
    const int l = tid & 63, w = tid >> 6;
    const int lg = l >> 4, li = l & 15;
    const int pi = i0 + w;

    __shared__ unsigned short curl[32][CP];
    __shared__ unsigned short intr[32][136];
    __shared__ unsigned short pref[4][136];
    __shared__ unsigned short wlds[KT * 4 * 64 * 8];   // 32 KB (C=128) / 24 KB

    // ---- stage W fragments (contiguous, all threads) ----
#pragma unroll
    for (int q = 0; q < KT; ++q) {
        int idx = q * 256 + tid;              // chunk index, < KT*256
        u16x8 v = *reinterpret_cast<const u16x8*>(&wf[(size_t)idx * 8]);
        *reinterpret_cast<u16x8*>(&wlds[idx * 8]) = v;
    }

    // ---- stage cur tile [32 j][C ch] as bf16 ----
    if (FROM_TAB) {
#pragma unroll
        for (int q = 0; q < 2; ++q) {
            int chn = q * 256 + tid;
            int jj = chn >> 4, c8 = chn & 15;
            u16x8 v = *reinterpret_cast<const u16x8*>(
                &cur0bf[((size_t)(b * T_ + j0 + jj) << 7) + c8 * 8]);
            *reinterpret_cast<u16x8*>(&curl[jj][c8 * 8]) = v;
        }
    } else {
        int jj = tid >> 3, c8 = tid & 7;
        const float* cp = &curprev[((size_t)(b * T_ + j0 + jj) << 6) + c8 * 8];
        float4 v0 = *reinterpret_cast<const float4*>(cp);
        float4 v1 = *reinterpret_cast<const float4*>(cp + 4);
        u16x8 r;
        r[0] = f2bf(v0.x); r[1] = f2bf(v0.y); r[2] = f2bf(v0.z); r[3] = f2bf(v0.w);
        r[4] = f2bf(v1.x); r[5] = f2bf(v1.y); r[6] = f2bf(v1.z); r[7] = f2bf(v1.w);
        *reinterpret_cast<u16x8*>(&curl[jj][c8 * 8]) = r;
    }

    if (!diag) {
        // ---- intra tile: contiguous copy ----
#pragma unroll
        for (int q = 0; q < 2; ++q) {
            int chn = q * 256 + tid;
            int jj = chn >> 4, c8 = chn & 15;
            u16x8 v = *reinterpret_cast<const u16x8*>(
                &intra[((size_t)((b * 16 + jt) * 32 + jj) << 7) + c8 * 8]);
            *reinterpret_cast<u16x8*>(&intr[jj][c8 * 8]) = v;
        }
        // ---- prefix queries: 4 i's x 16 chunks, range [i, j0-1] ----
        if (tid < 64) {
            int isel = tid >> 4, c8 = tid & 15;
            int i = i0 + isel;
            int len = j0 - i;                  // >= 1 (non-diag)
            int kk = 31 - __clz(len);
            int t2 = j0 - (1 << kk);
            const unsigned short* tab = (c8 < 8) ? tabmax : tabmin;
            int cc = (c8 & 7) * 8;
            u16x8 va = *reinterpret_cast<const u16x8*>(&tab[(((size_t)(kk * B_ + b) * T_ + i) << 6) + cc]);
            u16x8 vb = *reinterpret_cast<const u16x8*>(&tab[(((size_t)(kk * B_ + b) * T_ + t2) << 6) + cc]);
            u16x8 r;
#pragma unroll
            for (int e = 0; e < 8; ++e)
                r[e] = (c8 < 8) ? maxbits(va[e], vb[e]) : minbits(va[e], vb[e]);
            *reinterpret_cast<u16x8*>(&pref[isel][c8 * 8]) = r;
        }
    }
    __syncthreads();

    // ---- diag query params (per s) ----
    int kk_q[2], t2_q[2];
    if (diag) {
#pragma unroll
        for (int s = 0; s < 2; ++s) {
            int pj = j0 + 16 * s + li;
            int je = (pj < pi) ? pi : pj;
            int len = je - pi + 1;
            kk_q[s] = 31 - __clz(len);
            t2_q[s] = je + 1 - (1 << kk_q[s]);
        }
    }

    // ---- GEMM: wave w -> i = i0+w; W from LDS ----
    f32x4 acc[2][4];
#pragma unroll
    for (int s = 0; s < 2; ++s)
#pragma unroll
        for (int nt = 0; nt < 4; ++nt) acc[s][nt] = (f32x4){0.f, 0.f, 0.f, 0.f};

#pragma unroll
    for (int kt = 0; kt < KT; ++kt) {
        bf16x8 wfr[4];
#pragma unroll
        for (int nt = 0; nt < 4; ++nt)
            wfr[nt] = *reinterpret_cast<const bf16x8*>(&wlds[((kt * 4 + nt) * 64 + l) * 8]);

#pragma unroll
        for (int s = 0; s < 2; ++s) {
            const int pjj = 16 * s + li;
            bf16x8 av;
            if (kt < KTC) {
                av = *reinterpret_cast<const bf16x8*>(&curl[pjj][kt * 32 + lg * 8]);
            } else {
                const int krt = kt - KTC;
                if (!diag) {
                    u16x8 iv = *reinterpret_cast<const u16x8*>(&intr[pjj][(krt * 4 + lg) * 8]);
                    u16x8 pv = *reinterpret_cast<const u16x8*>(&pref[w][(krt * 4 + lg) * 8]);
                    if (krt < 2) {
#pragma unroll
                        for (int e = 0; e < 8; ++e) av[e] = (short)maxbits(iv[e], pv[e]);
                    } else {
#pragma unroll
                        for (int e = 0; e < 8; ++e) av[e] = (short)minbits(iv[e], pv[e]);
                    }
                } else {
                    const int c8 = krt * 4 + lg;
                    const unsigned short* tab = (krt < 2) ? tabmax : tabmin;
                    const int cc = (c8 & 7) * 8;
                    const int kk = kk_q[0], t2v = t2_q[0];
                    const int kk1 = kk_q[1], t2v1 = t2_q[1];
                    const int kku = (s == 0) ? kk : kk1;
                    const int t2u = (s == 0) ? t2v : t2v1;
                    u16x8 va = *reinterpret_cast<const u16x8*>(&tab[(((size_t)(kku * B_ + b) * T_ + pi) << 6) + cc]);
                    u16x8 vb = *reinterpret_cast<const u16x8*>(&tab[(((size_t)(kku * B_ + b) * T_ + t2u) << 6) + cc]);
                    if (krt < 2) {
#pragma unroll
                        for (int e = 0; e < 8; ++e) av[e] = (short)maxbits(va[e], vb[e]);
                    } else {
#pragma unroll
                        for (int e = 0; e < 8; ++e) av[e] = (short)minbits(va[e], vb[e]);
                    }
                }
            }
#pragma unroll
            for (int nt = 0; nt < 4; ++nt)
                acc[s][nt] = __builtin_amdgcn_mfma_f32_16x16x32_bf16(av, wfr[nt], acc[s][nt], 0, 0, 0);
        }
    }

    // ---- epilogue: wave-local max over valid jj, +bias, sigmoid, atomicMax ----
#pragma unroll
    for (int nt = 0; nt < 4; ++nt) {
        float vm = -1e9f;
#pragma unroll
        for (int s = 0; s < 2; ++s)
#pragma unroll
            for (int r = 0; r < 4; ++r) {
                int jj = 16 * s + lg * 4 + r;
                if (!diag || (j0 + jj >= pi)) vm = fmaxf(vm, acc[s][nt][r]);
            }
        vm = fmaxf(vm, __shfl_xor(vm, 16));
        vm = fmaxf(vm, __shfl_xor(vm, 32));
        if (l < 16) {
            int o = nt * 16 + li;
            float h = 1.0f / (1.0f + __expf(-(vm + bias[o])));
            atomicMax((int*)out + (((size_t)(b * T_ + pi) << 6) + o), __float_as_int(h));
        }
    }
}

// ---------------------------------------------------------------------------
extern "C" void kernel_launch(void* const* d_in, const int* in_sizes, int n_in,
                              void* d_out, int out_size, void* d_ws, size_t ws_size,
                              hipStream_t stream) {
    const float* f  = (const float*)d_in[0];
    const float* W0 = (const float*)d_in[1];
    const float* b0 = (const float*)d_in[2];
    const float* W1 = (const float*)d_in[3];
    const float* b1 = (const float*)d_in[4];
    const float* W2 = (const float*)d_in[5];
    const float* b2 = (const float*)d_in[6];
    float* outp = (float*)d_out;

    // workspace layout
    unsigned short* tabmax = (unsigned short*)d_ws;               // 10*B*T*64
    unsigned short* tabmin = tabmax + 10 * B_ * T_ * 64;          // 10*B*T*64
    unsigned short* wf     = tabmin + 10 * B_ * T_ * 64;          // 3*32*64*8
    unsigned short* cur0bf = wf + 3 * 32 * 64 * 8;                // B*T*128
    unsigned short* intra  = cur0bf + B_ * T_ * 128;              // B*16*32*128
    float* cur1 = (float*)(intra + B_ * 16 * 32 * 128);           // [B,T,64]
    float* cur2 = cur1 + B_ * T_ * 64;                            // [B,T,64]

    prep_kernel<<<dim3(267), dim3(512), 0, stream>>>(f, W0, W1, W2,
                                                     tabmax, tabmin, wf,
                                                     cur0bf, intra,
                                                     cur1, cur2, outp);

    const dim3 pgrid(B_ * NBLK_PER_B);
    pair_kernel<128, true ><<<pgrid, dim3(256), 0, stream>>>(tabmax, tabmin, cur0bf, intra,
                                                             nullptr, wf + 0 * 32 * 64 * 8, b0, cur1);
    pair_kernel<64,  false><<<pgrid, dim3(256), 0, stream>>>(tabmax, tabmin, cur0bf, intra,
                                                             cur1, wf + 1 * 32 * 64 * 8, b1, cur2);
    pair_kernel<64,  false><<<pgrid, dim3(256), 0, stream>>>(tabmax, tabmin, cur0bf, intra,
                                                             cur2, wf + 2 * 32 * 64 * 8, b2, outp);
}

// Round 12
// 78.226 us; speedup vs baseline: 1.5861x; 1.0300x over previous
//
#include <hip/hip_runtime.h>
#include <hip/hip_bf16.h>
#include <math.h>

#define B_ 2
#define T_ 512
#define D_ 64
#define NBLK8_PER_B 544   // 64 diag + 480 non-diag

typedef __attribute__((ext_vector_type(8))) short bf16x8;
typedef __attribute__((ext_vector_type(8))) unsigned short u16x8;
typedef __attribute__((ext_vector_type(4))) float f32x4;

static __device__ __forceinline__ unsigned short f2bf(float v) {
    __hip_bfloat16 h = __float2bfloat16(v);
    return *reinterpret_cast<unsigned short*>(&h);
}
static __device__ __forceinline__ float bf2f(unsigned short u) {
    return __uint_as_float(((unsigned)u) << 16);
}
static __device__ __forceinline__ unsigned short maxbits(unsigned short a, unsigned short b) {
    float m = fmaxf(bf2f(a), bf2f(b));
    return (unsigned short)(__float_as_uint(m) >> 16);
}
static __device__ __forceinline__ unsigned short minbits(unsigned short a, unsigned short b) {
    float m = fminf(bf2f(a), bf2f(b));
    return (unsigned short)(__float_as_uint(m) >> 16);
}

// ---------------------------------------------------------------------------
// Fused prep (267 heterogeneous blocks, 512 threads):
//  [0,8)    sparse tables tab[k][b][t][c], k=0..9, bf16
//  [8,11)   W fragment pack (full K)
//  [11,139) cur0bf[b][t][128] = bf16 suffix max/min of f (Hillis-Steele)
//  [139,171) intra[b][jt][jj][128] = running max/min within 32-j tile (scan)
//  [171,267) zero cur1 / cur2 / out
// ---------------------------------------------------------------------------
__global__ __launch_bounds__(512) void prep_kernel(
    const float* __restrict__ f,
    const float* __restrict__ W0, const float* __restrict__ W1, const float* __restrict__ W2,
    unsigned short* __restrict__ tmax, unsigned short* __restrict__ tmin,
    unsigned short* __restrict__ wf,
    unsigned short* __restrict__ cur0bf, unsigned short* __restrict__ intra,
    float* __restrict__ z0, float* __restrict__ z1, float* __restrict__ z2) {

    __shared__ unsigned short lmax[512][16];
    __shared__ unsigned short lmin[512][16];

    const int blk = blockIdx.x;
    const int tid = threadIdx.x;

    if (blk < 8) {
        const int b = blk & 1;
        const int c0 = (blk >> 1) * 16;
        const int t = tid;

        u16x8 mx[2], mn[2];
#pragma unroll
        for (int h = 0; h < 2; ++h) {
            const float* fp = &f[((size_t)(b * T_ + t) << 6) + c0 + h * 8];
#pragma unroll
            for (int e = 0; e < 8; ++e) {
                unsigned short u = f2bf(fp[e]);
                mx[h][e] = u; mn[h][e] = u;
            }
            size_t base = ((size_t)(b * T_ + t) << 6) + c0 + h * 8;
            *reinterpret_cast<u16x8*>(&tmax[base]) = mx[h];
            *reinterpret_cast<u16x8*>(&tmin[base]) = mn[h];
        }
        for (int k = 1; k <= 9; ++k) {
            *reinterpret_cast<u16x8*>(&lmax[t][0]) = mx[0];
            *reinterpret_cast<u16x8*>(&lmax[t][8]) = mx[1];
            *reinterpret_cast<u16x8*>(&lmin[t][0]) = mn[0];
            *reinterpret_cast<u16x8*>(&lmin[t][8]) = mn[1];
            __syncthreads();
            int t2 = t + (1 << (k - 1));
            if (t2 > T_ - 1) t2 = T_ - 1;
            u16x8 qx0 = *reinterpret_cast<const u16x8*>(&lmax[t2][0]);
            u16x8 qx1 = *reinterpret_cast<const u16x8*>(&lmax[t2][8]);
            u16x8 qn0 = *reinterpret_cast<const u16x8*>(&lmin[t2][0]);
            u16x8 qn1 = *reinterpret_cast<const u16x8*>(&lmin[t2][8]);
#pragma unroll
            for (int e = 0; e < 8; ++e) {
                mx[0][e] = maxbits(mx[0][e], qx0[e]);
                mx[1][e] = maxbits(mx[1][e], qx1[e]);
                mn[0][e] = minbits(mn[0][e], qn0[e]);
                mn[1][e] = minbits(mn[1][e], qn1[e]);
            }
            size_t base = ((size_t)((k * B_ + b) * T_ + t) << 6) + c0;
            *reinterpret_cast<u16x8*>(&tmax[base]) = mx[0];
            *reinterpret_cast<u16x8*>(&tmax[base + 8]) = mx[1];
            *reinterpret_cast<u16x8*>(&tmin[base]) = mn[0];
            *reinterpret_cast<u16x8*>(&tmin[base + 8]) = mn[1];
            __syncthreads();
        }
    } else if (blk < 11) {
        const int layer = blk - 8;
        const float* W = (layer == 0) ? W0 : ((layer == 1) ? W1 : W2);
        const int FRS = (layer == 0) ? 32 : 24;
        const int l = tid & 63;
        for (int fr = tid >> 6; fr < FRS; fr += 8) {
            int kt = fr >> 2, nt = fr & 3;
#pragma unroll
            for (int e = 0; e < 8; ++e) {
                int row = kt * 32 + ((l >> 4) << 3) + e;
                int col = nt * 16 + (l & 15);
                wf[((size_t)(layer * 32 + fr) * 64 + l) * 8 + e] = f2bf(W[row * 64 + col]);
            }
        }
    } else if (blk < 139) {
        const int x = blk - 11;
        const int c = x & 63, b = x >> 6;
        const int t = tid;
        float* smax = reinterpret_cast<float*>(lmax);
        float* smin = reinterpret_cast<float*>(lmin);
        float v = f[((size_t)(b * T_ + t) << 6) + c];
        smax[t] = v; smin[t] = v;
        __syncthreads();
        for (int off = 1; off < 512; off <<= 1) {
            float a = (t + off < 512) ? smax[t + off] : -1e30f;
            float m = (t + off < 512) ? smin[t + off] : 1e30f;
            __syncthreads();
            smax[t] = fmaxf(smax[t], a);
            smin[t] = fminf(smin[t], m);
            __syncthreads();
        }
        cur0bf[((size_t)(b * T_ + t) << 7) + c] = f2bf(smax[t]);
        cur0bf[((size_t)(b * T_ + t) << 7) + 64 + c] = f2bf(smin[t]);
    } else if (blk < 171) {
        const int x = blk - 139;
        const int jt = x & 15, b = x >> 4;
        const int jj = tid >> 4, c8 = tid & 15;
        const bool ismin = c8 >= 8;
        unsigned short (*sc)[128] = reinterpret_cast<unsigned short (*)[128]>(lmax);

        const float* fp = &f[((size_t)(b * T_ + jt * 32 + jj) << 6) + (c8 & 7) * 8];
        u16x8 r;
#pragma unroll
        for (int e = 0; e < 8; ++e) r[e] = f2bf(fp[e]);

#pragma unroll
        for (int off = 1; off < 32; off <<= 1) {
            *reinterpret_cast<u16x8*>(&sc[jj][c8 * 8]) = r;
            __syncthreads();
            if (jj >= off) {
                u16x8 q = *reinterpret_cast<const u16x8*>(&sc[jj - off][c8 * 8]);
#pragma unroll
                for (int e = 0; e < 8; ++e)
                    r[e] = ismin ? minbits(r[e], q[e]) : maxbits(r[e], q[e]);
            }
            __syncthreads();
        }
        *reinterpret_cast<u16x8*>(&intra[((size_t)((b * 16 + jt) * 32 + jj) << 7) + c8 * 8]) = r;
    } else {
        int fi = (blk - 171) * 512 + tid;
        float4 z = {0.f, 0.f, 0.f, 0.f};
        if (fi < 16384)       reinterpret_cast<float4*>(z0)[fi] = z;
        else if (fi < 32768)  reinterpret_cast<float4*>(z1)[fi - 16384] = z;
        else                  reinterpret_cast<float4*>(z2)[fi - 32768] = z;
    }
}

// ---------------------------------------------------------------------------
// Pair GEMM over triangular tiles.  Block = 512 threads = 8 waves;
// (b, 8 i's, 32 j's); wave w owns row i = i0+w with the same acc[2][4]
// register footprint as the 4-wave version.  curl/intr/wlds staging is
// amortized over 8 waves; 52 KB LDS x 3 blocks/CU = 24 waves/CU.
// Diag blocks (it >= 4*jt) ordered first; per-lane table queries there.
// ---------------------------------------------------------------------------
template <int C, bool FROM_TAB>
__global__ __launch_bounds__(512) void pair_kernel(
    const unsigned short* __restrict__ tabmax,
    const unsigned short* __restrict__ tabmin,
    const unsigned short* __restrict__ cur0bf,  // [B,T,128] bf16
    const unsigned short* __restrict__ intra,   // [B,16,32,128] bf16
    const float* __restrict__ curprev,          // fp32 [B,T,64]; unused if FROM_TAB
    const unsigned short* __restrict__ wf,      // layer base, fragment order
    const float* __restrict__ bias,
    float* __restrict__ out) {

    constexpr int KTC = C / 32;       // 4 or 2
    constexpr int KT = KTC + 4;       // 8 or 6
    constexpr int CP = (C == 128) ? 136 : 72;

    // ---- decode: diag blocks first (m < 64), then non-diag ----
    int m = blockIdx.x;
    int b = 0;
    if (m >= NBLK8_PER_B) { b = 1; m -= NBLK8_PER_B; }
    int jt, it;
    bool diag;
    if (m < 64) {
        diag = true;
        jt = m >> 2;
        it = 4 * jt + (m & 3);
    } else {
        diag = false;
        int m2 = m - 64;
        jt = 1;
        while (m2 >= 2 * jt * (jt + 1)) ++jt;     // <=14 iters
        it = m2 - 2 * jt * (jt - 1);              // 0 .. 4*jt-1
    }
    const int i0 = it * 8, j0 = jt * 32;

    const int tid = threadIdx.x;
    const int l = tid & 63, w = tid >> 6;         // w = 0..7
    const int lg = l >> 4, li = l & 15;
    const int pi = i0 + w;

    __shared__ unsigned short curl[32][CP];
    __shared__ unsigned short intr[32][136];
    __shared__ unsigned short pref[8][136];
    __shared__ unsigned short wlds[KT * 4 * 64 * 8];   // 32 KB (C=128) / 24 KB

    // ---- stage W fragments (contiguous, all threads) ----
#pragma unroll
    for (int q = 0; q < KT / 2; ++q) {
        int idx = q * 512 + tid;              // chunk index, < KT*256
        u16x8 v = *reinterpret_cast<const u16x8*>(&wf[(size_t)idx * 8]);
        *reinterpret_cast<u16x8*>(&wlds[idx * 8]) = v;
    }

    // ---- stage cur tile [32 j][C ch] as bf16 ----
    if (FROM_TAB) {
        int jj = tid >> 4, c8 = tid & 15;     // 512 chunks exactly
        u16x8 v = *reinterpret_cast<const u16x8*>(
            &cur0bf[((size_t)(b * T_ + j0 + jj) << 7) + c8 * 8]);
        *reinterpret_cast<u16x8*>(&curl[jj][c8 * 8]) = v;
    } else if (tid < 256) {
        int jj = tid >> 3, c8 = tid & 7;
        const float* cp = &curprev[((size_t)(b * T_ + j0 + jj) << 6) + c8 * 8];
        float4 v0 = *reinterpret_cast<const float4*>(cp);
        float4 v1 = *reinterpret_cast<const float4*>(cp + 4);
        u16x8 r;
        r[0] = f2bf(v0.x); r[1] = f2bf(v0.y); r[2] = f2bf(v0.z); r[3] = f2bf(v0.w);
        r[4] = f2bf(v1.x); r[5] = f2bf(v1.y); r[6] = f2bf(v1.z); r[7] = f2bf(v1.w);
        *reinterpret_cast<u16x8*>(&curl[jj][c8 * 8]) = r;
    }

    if (!diag) {
        // ---- intra tile: contiguous copy (512 chunks exactly) ----
        {
            int jj = tid >> 4, c8 = tid & 15;
            u16x8 v = *reinterpret_cast<const u16x8*>(
                &intra[((size_t)((b * 16 + jt) * 32 + jj) << 7) + c8 * 8]);
            *reinterpret_cast<u16x8*>(&intr[jj][c8 * 8]) = v;
        }
        // ---- prefix queries: 8 i's x 16 chunks, range [i, j0-1] ----
        if (tid < 128) {
            int isel = tid >> 4, c8 = tid & 15;
            int i = i0 + isel;
            int len = j0 - i;                  // >= 1 (non-diag)
            int kk = 31 - __clz(len);
            int t2 = j0 - (1 << kk);
            const unsigned short* tab = (c8 < 8) ? tabmax : tabmin;
            int cc = (c8 & 7) * 8;
            u16x8 va = *reinterpret_cast<const u16x8*>(&tab[(((size_t)(kk * B_ + b) * T_ + i) << 6) + cc]);
            u16x8 vb = *reinterpret_cast<const u16x8*>(&tab[(((size_t)(kk * B_ + b) * T_ + t2) << 6) + cc]);
            u16x8 r;
#pragma unroll
            for (int e = 0; e < 8; ++e)
                r[e] = (c8 < 8) ? maxbits(va[e], vb[e]) : minbits(va[e], vb[e]);
            *reinterpret_cast<u16x8*>(&pref[isel][c8 * 8]) = r;
        }
    }
    __syncthreads();

    // ---- diag query params (per s) ----
    int kk_q[2], t2_q[2];
    if (diag) {
#pragma unroll
        for (int s = 0; s < 2; ++s) {
            int pj = j0 + 16 * s + li;
            int je = (pj < pi) ? pi : pj;
            int len = je - pi + 1;
            kk_q[s] = 31 - __clz(len);
            t2_q[s] = je + 1 - (1 << kk_q[s]);
        }
    }

    // ---- GEMM: wave w -> i = i0+w; W from LDS ----
    f32x4 acc[2][4];
#pragma unroll
    for (int s = 0; s < 2; ++s)
#pragma unroll
        for (int nt = 0; nt < 4; ++nt) acc[s][nt] = (f32x4){0.f, 0.f, 0.f, 0.f};

#pragma unroll
    for (int kt = 0; kt < KT; ++kt) {
        bf16x8 wfr[4];
#pragma unroll
        for (int nt = 0; nt < 4; ++nt)
            wfr[nt] = *reinterpret_cast<const bf16x8*>(&wlds[((kt * 4 + nt) * 64 + l) * 8]);

#pragma unroll
        for (int s = 0; s < 2; ++s) {
            const int pjj = 16 * s + li;
            bf16x8 av;
            if (kt < KTC) {
                av = *reinterpret_cast<const bf16x8*>(&curl[pjj][kt * 32 + lg * 8]);
            } else {
                const int krt = kt - KTC;
                if (!diag) {
                    u16x8 iv = *reinterpret_cast<const u16x8*>(&intr[pjj][(krt * 4 + lg) * 8]);
                    u16x8 pv = *reinterpret_cast<const u16x8*>(&pref[w][(krt * 4 + lg) * 8]);
                    if (krt < 2) {
#pragma unroll
                        for (int e = 0; e < 8; ++e) av[e] = (short)maxbits(iv[e], pv[e]);
                    } else {
#pragma unroll
                        for (int e = 0; e < 8; ++e) av[e] = (short)minbits(iv[e], pv[e]);
                    }
                } else {
                    const int c8 = krt * 4 + lg;
                    const unsigned short* tab = (krt < 2) ? tabmax : tabmin;
                    const int cc = (c8 & 7) * 8;
                    const int kku = kk_q[s], t2u = t2_q[s];
                    u16x8 va = *reinterpret_cast<const u16x8*>(&tab[(((size_t)(kku * B_ + b) * T_ + pi) << 6) + cc]);
                    u16x8 vb = *reinterpret_cast<const u16x8*>(&tab[(((size_t)(kku * B_ + b) * T_ + t2u) << 6) + cc]);
                    if (krt < 2) {
#pragma unroll
                        for (int e = 0; e < 8; ++e) av[e] = (short)maxbits(va[e], vb[e]);
                    } else {
#pragma unroll
                        for (int e = 0; e < 8; ++e) av[e] = (short)minbits(va[e], vb[e]);
                    }
                }
            }
#pragma unroll
            for (int nt = 0; nt < 4; ++nt)
                acc[s][nt] = __builtin_amdgcn_mfma_f32_16x16x32_bf16(av, wfr[nt], acc[s][nt], 0, 0, 0);
        }
    }

    // ---- epilogue: wave-local max over valid jj, +bias, sigmoid, atomicMax ----
#pragma unroll
    for (int nt = 0; nt < 4; ++nt) {
        float vm = -1e9f;
#pragma unroll
        for (int s = 0; s < 2; ++s)
#pragma unroll
            for (int r = 0; r < 4; ++r) {
                int jj = 16 * s + lg * 4 + r;
                if (!diag || (j0 + jj >= pi)) vm = fmaxf(vm, acc[s][nt][r]);
            }
        vm = fmaxf(vm, __shfl_xor(vm, 16));
        vm = fmaxf(vm, __shfl_xor(vm, 32));
        if (l < 16) {
            int o = nt * 16 + li;
            float h = 1.0f / (1.0f + __expf(-(vm + bias[o])));
            atomicMax((int*)out + (((size_t)(b * T_ + pi) << 6) + o), __float_as_int(h));
        }
    }
}

// ---------------------------------------------------------------------------
extern "C" void kernel_launch(void* const* d_in, const int* in_sizes, int n_in,
                              void* d_out, int out_size, void* d_ws, size_t ws_size,
                              hipStream_t stream) {
    const float* f  = (const float*)d_in[0];
    const float* W0 = (const float*)d_in[1];
    const float* b0 = (const float*)d_in[2];
    const float* W1 = (const float*)d_in[3];
    const float* b1 = (const float*)d_in[4];
    const float* W2 = (const float*)d_in[5];
    const float* b2 = (const float*)d_in[6];
    float* outp = (float*)d_out;

    // workspace layout
    unsigned short* tabmax = (unsigned short*)d_ws;               // 10*B*T*64
    unsigned short* tabmin = tabmax + 10 * B_ * T_ * 64;          // 10*B*T*64
    unsigned short* wf     = tabmin + 10 * B_ * T_ * 64;          // 3*32*64*8
    unsigned short* cur0bf = wf + 3 * 32 * 64 * 8;                // B*T*128
    unsigned short* intra  = cur0bf + B_ * T_ * 128;              // B*16*32*128
    float* cur1 = (float*)(intra + B_ * 16 * 32 * 128);           // [B,T,64]
    float* cur2 = cur1 + B_ * T_ * 64;                            // [B,T,64]

    prep_kernel<<<dim3(267), dim3(512), 0, stream>>>(f, W0, W1, W2,
                                                     tabmax, tabmin, wf,
                                                     cur0bf, intra,
                                                     cur1, cur2, outp);

    const dim3 pgrid(B_ * NBLK8_PER_B);
    pair_kernel<128, true ><<<pgrid, dim3(512), 0, stream>>>(tabmax, tabmin, cur0bf, intra,
                                                             nullptr, wf + 0 * 32 * 64 * 8, b0, cur1);
    pair_kernel<64,  false><<<pgrid, dim3(512), 0, stream>>>(tabmax, tabmin, cur0bf, intra,
                                                             cur1, wf + 1 * 32 * 64 * 8, b1, cur2);
    pair_kernel<64,  false><<<pgrid, dim3(512), 0, stream>>>(tabmax, tabmin, cur0bf, intra,
                                                             cur2, wf + 2 * 32 * 64 * 8, b2, outp);
}

// Round 13
// 77.588 us; speedup vs baseline: 1.5991x; 1.0082x over previous
//
#include <hip/hip_runtime.h>
#include <hip/hip_bf16.h>
#include <math.h>

#define B_ 2
#define T_ 512
#define D_ 64

typedef __attribute__((ext_vector_type(8))) short bf16x8;
typedef __attribute__((ext_vector_type(8))) unsigned short u16x8;
typedef __attribute__((ext_vector_type(4))) float f32x4;

static __device__ __forceinline__ unsigned short f2bf(float v) {
    __hip_bfloat16 h = __float2bfloat16(v);
    return *reinterpret_cast<unsigned short*>(&h);
}
static __device__ __forceinline__ float bf2f(unsigned short u) {
    return __uint_as_float(((unsigned)u) << 16);
}
static __device__ __forceinline__ unsigned short maxbits(unsigned short a, unsigned short b) {
    float m = fmaxf(bf2f(a), bf2f(b));
    return (unsigned short)(__float_as_uint(m) >> 16);
}
static __device__ __forceinline__ unsigned short minbits(unsigned short a, unsigned short b) {
    float m = fminf(bf2f(a), bf2f(b));
    return (unsigned short)(__float_as_uint(m) >> 16);
}

// ---------------------------------------------------------------------------
// Fused prep (139 heterogeneous blocks, 512 threads):
//  [0,8)   sparse tables tab[k][b][t][c], k=0..9, bf16
//  [8,11)  W r-part fragment pack (rows C..C+128, 16 frags/layer)
//  [11,43) intra[b][jt][jj][128] = running max/min within 32-j tile (scan)
//  [43,139) zero cur1 / cur2 / out
// ---------------------------------------------------------------------------
__global__ __launch_bounds__(512) void prep_kernel(
    const float* __restrict__ f,
    const float* __restrict__ W0, const float* __restrict__ W1, const float* __restrict__ W2,
    unsigned short* __restrict__ tmax, unsigned short* __restrict__ tmin,
    unsigned short* __restrict__ wf,
    unsigned short* __restrict__ intra,
    float* __restrict__ z0, float* __restrict__ z1, float* __restrict__ z2) {

    __shared__ unsigned short lmax[512][16];
    __shared__ unsigned short lmin[512][16];

    const int blk = blockIdx.x;
    const int tid = threadIdx.x;

    if (blk < 8) {
        const int b = blk & 1;
        const int c0 = (blk >> 1) * 16;
        const int t = tid;

        u16x8 mx[2], mn[2];
#pragma unroll
        for (int h = 0; h < 2; ++h) {
            const float* fp = &f[((size_t)(b * T_ + t) << 6) + c0 + h * 8];
#pragma unroll
            for (int e = 0; e < 8; ++e) {
                unsigned short u = f2bf(fp[e]);
                mx[h][e] = u; mn[h][e] = u;
            }
            size_t base = ((size_t)(b * T_ + t) << 6) + c0 + h * 8;
            *reinterpret_cast<u16x8*>(&tmax[base]) = mx[h];
            *reinterpret_cast<u16x8*>(&tmin[base]) = mn[h];
        }
        for (int k = 1; k <= 9; ++k) {
            *reinterpret_cast<u16x8*>(&lmax[t][0]) = mx[0];
            *reinterpret_cast<u16x8*>(&lmax[t][8]) = mx[1];
            *reinterpret_cast<u16x8*>(&lmin[t][0]) = mn[0];
            *reinterpret_cast<u16x8*>(&lmin[t][8]) = mn[1];
            __syncthreads();
            int t2 = t + (1 << (k - 1));
            if (t2 > T_ - 1) t2 = T_ - 1;
            u16x8 qx0 = *reinterpret_cast<const u16x8*>(&lmax[t2][0]);
            u16x8 qx1 = *reinterpret_cast<const u16x8*>(&lmax[t2][8]);
            u16x8 qn0 = *reinterpret_cast<const u16x8*>(&lmin[t2][0]);
            u16x8 qn1 = *reinterpret_cast<const u16x8*>(&lmin[t2][8]);
#pragma unroll
            for (int e = 0; e < 8; ++e) {
                mx[0][e] = maxbits(mx[0][e], qx0[e]);
                mx[1][e] = maxbits(mx[1][e], qx1[e]);
                mn[0][e] = minbits(mn[0][e], qn0[e]);
                mn[1][e] = minbits(mn[1][e], qn1[e]);
            }
            size_t base = ((size_t)((k * B_ + b) * T_ + t) << 6) + c0;
            *reinterpret_cast<u16x8*>(&tmax[base]) = mx[0];
            *reinterpret_cast<u16x8*>(&tmax[base + 8]) = mx[1];
            *reinterpret_cast<u16x8*>(&tmin[base]) = mn[0];
            *reinterpret_cast<u16x8*>(&tmin[base + 8]) = mn[1];
            __syncthreads();
        }
    } else if (blk < 11) {
        // ---- W r-part fragment pack: rows Coff..Coff+128 -> 16 frags ----
        const int layer = blk - 8;
        const float* W = (layer == 0) ? W0 : ((layer == 1) ? W1 : W2);
        const int Coff = (layer == 0) ? 128 : 64;
        const int l = tid & 63;
#pragma unroll
        for (int q = 0; q < 2; ++q) {
            int fr = (tid >> 6) + q * 8;          // 0..15
            int kt = fr >> 2, nt = fr & 3;
#pragma unroll
            for (int e = 0; e < 8; ++e) {
                int row = Coff + kt * 32 + ((l >> 4) << 3) + e;
                int col = nt * 16 + (l & 15);
                wf[((size_t)(layer * 16 + fr) * 64 + l) * 8 + e] = f2bf(W[row * 64 + col]);
            }
        }
    } else if (blk < 43) {
        const int x = blk - 11;
        const int jt = x & 15, b = x >> 4;
        const int jj = tid >> 4, c8 = tid & 15;
        const bool ismin = c8 >= 8;
        unsigned short (*sc)[128] = reinterpret_cast<unsigned short (*)[128]>(lmax);

        const float* fp = &f[((size_t)(b * T_ + jt * 32 + jj) << 6) + (c8 & 7) * 8];
        u16x8 r;
#pragma unroll
        for (int e = 0; e < 8; ++e) r[e] = f2bf(fp[e]);

#pragma unroll
        for (int off = 1; off < 32; off <<= 1) {
            *reinterpret_cast<u16x8*>(&sc[jj][c8 * 8]) = r;
            __syncthreads();
            if (jj >= off) {
                u16x8 q = *reinterpret_cast<const u16x8*>(&sc[jj - off][c8 * 8]);
#pragma unroll
                for (int e = 0; e < 8; ++e)
                    r[e] = ismin ? minbits(r[e], q[e]) : maxbits(r[e], q[e]);
            }
            __syncthreads();
        }
        *reinterpret_cast<u16x8*>(&intra[((size_t)((b * 16 + jt) * 32 + jj) << 7) + c8 * 8]) = r;
    } else {
        int fi = (blk - 43) * 512 + tid;   // float4 index, 0..49151
        float4 z = {0.f, 0.f, 0.f, 0.f};
        if (fi < 16384)       reinterpret_cast<float4*>(z0)[fi] = z;
        else if (fi < 32768)  reinterpret_cast<float4*>(z1)[fi - 16384] = z;
        else                  reinterpret_cast<float4*>(z2)[fi - 32768] = z;
    }
}

// ---------------------------------------------------------------------------
// g0[b,t,o] = bias[o] + sum_{c<128} cur0[b,t,c] * W0[c][o]
// cur0 row built from sparse-table suffix queries [t, T-1] (bf16 -> fp32).
// Block = 4 rows x 64 outputs.
// ---------------------------------------------------------------------------
__global__ __launch_bounds__(256) void g0_kernel(
    const unsigned short* __restrict__ tabmax,
    const unsigned short* __restrict__ tabmin,
    const float* __restrict__ W0, const float* __restrict__ bias,
    float* __restrict__ g) {

    __shared__ float cur_lds[4][128];

    const int tid = threadIdx.x;
    const int bt0 = blockIdx.x * 4;

    if (tid < 64) {
        int isel = tid >> 4, c8 = tid & 15;
        int bt = bt0 + isel;
        int b = bt >> 9, t = bt & 511;
        int len = T_ - t;
        int kk = 31 - __clz(len);
        int t2 = T_ - (1 << kk);
        const unsigned short* tab = (c8 < 8) ? tabmax : tabmin;
        int cc = (c8 & 7) * 8;
        u16x8 va = *reinterpret_cast<const u16x8*>(&tab[(((size_t)(kk * B_ + b) * T_ + t) << 6) + cc]);
        u16x8 vb = *reinterpret_cast<const u16x8*>(&tab[(((size_t)(kk * B_ + b) * T_ + t2) << 6) + cc]);
#pragma unroll
        for (int e = 0; e < 8; ++e) {
            unsigned short r = (c8 < 8) ? maxbits(va[e], vb[e]) : minbits(va[e], vb[e]);
            cur_lds[isel][c8 * 8 + e] = bf2f(r);
        }
    }
    __syncthreads();

    const int r = tid >> 6, o = tid & 63;
    float s = bias[o];
#pragma unroll 8
    for (int c = 0; c < 128; ++c)
        s = fmaf(cur_lds[r][c], W0[c * 64 + o], s);
    g[((size_t)(bt0 + r) << 6) + o] = s;
}

// ---------------------------------------------------------------------------
// g[b,t,o] = bias[o] + sum_{c<64} cur[b,t,c] * W[c][o]   (fp32 cur)
// ---------------------------------------------------------------------------
__global__ __launch_bounds__(256) void g64_kernel(
    const float* __restrict__ cur, const float* __restrict__ W,
    const float* __restrict__ bias, float* __restrict__ g) {
    const int bt = blockIdx.x * 4 + (threadIdx.x >> 6);
    const int o = threadIdx.x & 63;
    float s = bias[o];
    const float* cp = &cur[(size_t)bt << 6];
#pragma unroll 8
    for (int c = 0; c < 64; ++c)
        s = fmaf(cp[c], W[c * 64 + o], s);
    g[((size_t)bt << 6) + o] = s;
}

// ---------------------------------------------------------------------------
// Pair GEMM, K = 128 (r-part only).  Block = 512 threads = 8 waves;
// (b, 8 i's, 32 j's); wave w owns row i = i0+w.  g added in the epilogue
// before the max (monotone).  W (16 KB) staged in LDS; diag blocks first.
// LDS ~36 KB -> 4 blocks/CU.
// ---------------------------------------------------------------------------
__global__ __launch_bounds__(512) void pair_kernel(
    const unsigned short* __restrict__ tabmax,
    const unsigned short* __restrict__ tabmin,
    const unsigned short* __restrict__ intra,   // [B,16,32,128] bf16
    const unsigned short* __restrict__ wf,      // layer base, 16 frags
    const float* __restrict__ g,                // [B,T,64] fp32
    float* __restrict__ out) {

    // ---- decode: diag blocks first (m < 128, b-interleaved), then non-diag ----
    int m = blockIdx.x;
    int b, jt, it;
    bool diag;
    if (m < 128) {
        diag = true;
        b = m & 1;
        int idx = m >> 1;            // 0..63
        jt = idx >> 2;
        it = 4 * jt + (idx & 3);
    } else {
        diag = false;
        int m2 = m - 128;
        b = m2 & 1;
        int m3 = m2 >> 1;            // 0..479
        jt = 1;
        while (m3 >= 2 * jt * (jt + 1)) ++jt;     // <=14 iters
        it = m3 - 2 * jt * (jt - 1);              // 0 .. 4*jt-1
    }
    const int i0 = it * 8, j0 = jt * 32;

    const int tid = threadIdx.x;
    const int l = tid & 63, w = tid >> 6;         // w = 0..7
    const int lg = l >> 4, li = l & 15;
    const int pi = i0 + w;

    __shared__ unsigned short intr[32][136];
    __shared__ unsigned short pref[8][136];
    __shared__ unsigned short wlds[16 * 64 * 8];   // 16 KB
    __shared__ float gl[32][68];

    // ---- stage W fragments (contiguous, 1024 chunks) ----
#pragma unroll
    for (int q = 0; q < 2; ++q) {
        int idx = q * 512 + tid;
        u16x8 v = *reinterpret_cast<const u16x8*>(&wf[(size_t)idx * 8]);
        *reinterpret_cast<u16x8*>(&wlds[idx * 8]) = v;
    }

    // ---- stage g tile [32 j][64 o] (512 float4 chunks) ----
    {
        int jj = tid >> 4, c4 = tid & 15;
        float4 v = *reinterpret_cast<const float4*>(&g[((size_t)(b * T_ + j0 + jj) << 6) + c4 * 4]);
        *reinterpret_cast<float4*>(&gl[jj][c4 * 4]) = v;
    }

    if (!diag) {
        // ---- intra tile: contiguous copy (512 chunks) ----
        {
            int jj = tid >> 4, c8 = tid & 15;
            u16x8 v = *reinterpret_cast<const u16x8*>(
                &intra[((size_t)((b * 16 + jt) * 32 + jj) << 7) + c8 * 8]);
            *reinterpret_cast<u16x8*>(&intr[jj][c8 * 8]) = v;
        }
        // ---- prefix queries: 8 i's x 16 chunks, range [i, j0-1] ----
        if (tid < 128) {
            int isel = tid >> 4, c8 = tid & 15;
            int i = i0 + isel;
            int len = j0 - i;                  // >= 1 (non-diag)
            int kk = 31 - __clz(len);
            int t2 = j0 - (1 << kk);
            const unsigned short* tab = (c8 < 8) ? tabmax : tabmin;
            int cc = (c8 & 7) * 8;
            u16x8 va = *reinterpret_cast<const u16x8*>(&tab[(((size_t)(kk * B_ + b) * T_ + i) << 6) + cc]);
            u16x8 vb = *reinterpret_cast<const u16x8*>(&tab[(((size_t)(kk * B_ + b) * T_ + t2) << 6) + cc]);
            u16x8 r;
#pragma unroll
            for (int e = 0; e < 8; ++e)
                r[e] = (c8 < 8) ? maxbits(va[e], vb[e]) : minbits(va[e], vb[e]);
            *reinterpret_cast<u16x8*>(&pref[isel][c8 * 8]) = r;
        }
    }
    __syncthreads();

    // ---- diag query params (per s) ----
    int kk_q[2], t2_q[2];
    if (diag) {
#pragma unroll
        for (int s = 0; s < 2; ++s) {
            int pj = j0 + 16 * s + li;
            int je = (pj < pi) ? pi : pj;
            int len = je - pi + 1;
            kk_q[s] = 31 - __clz(len);
            t2_q[s] = je + 1 - (1 << kk_q[s]);
        }
    }

    // ---- GEMM: K=128, 4 k-tiles; W from LDS ----
    f32x4 acc[2][4];
#pragma unroll
    for (int s = 0; s < 2; ++s)
#pragma unroll
        for (int nt = 0; nt < 4; ++nt) acc[s][nt] = (f32x4){0.f, 0.f, 0.f, 0.f};

#pragma unroll
    for (int krt = 0; krt < 4; ++krt) {
        bf16x8 wfr[4];
#pragma unroll
        for (int nt = 0; nt < 4; ++nt)
            wfr[nt] = *reinterpret_cast<const bf16x8*>(&wlds[((krt * 4 + nt) * 64 + l) * 8]);

#pragma unroll
        for (int s = 0; s < 2; ++s) {
            const int pjj = 16 * s + li;
            bf16x8 av;
            if (!diag) {
                u16x8 iv = *reinterpret_cast<const u16x8*>(&intr[pjj][(krt * 4 + lg) * 8]);
                u16x8 pv = *reinterpret_cast<const u16x8*>(&pref[w][(krt * 4 + lg) * 8]);
                if (krt < 2) {
#pragma unroll
                    for (int e = 0; e < 8; ++e) av[e] = (short)maxbits(iv[e], pv[e]);
                } else {
#pragma unroll
                    for (int e = 0; e < 8; ++e) av[e] = (short)minbits(iv[e], pv[e]);
                }
            } else {
                const int c8 = krt * 4 + lg;
                const unsigned short* tab = (krt < 2) ? tabmax : tabmin;
                const int cc = (c8 & 7) * 8;
                const int kku = kk_q[s], t2u = t2_q[s];
                u16x8 va = *reinterpret_cast<const u16x8*>(&tab[(((size_t)(kku * B_ + b) * T_ + pi) << 6) + cc]);
                u16x8 vb = *reinterpret_cast<const u16x8*>(&tab[(((size_t)(kku * B_ + b) * T_ + t2u) << 6) + cc]);
                if (krt < 2) {
#pragma unroll
                    for (int e = 0; e < 8; ++e) av[e] = (short)maxbits(va[e], vb[e]);
                } else {
#pragma unroll
                    for (int e = 0; e < 8; ++e) av[e] = (short)minbits(va[e], vb[e]);
                }
            }
#pragma unroll
            for (int nt = 0; nt < 4; ++nt)
                acc[s][nt] = __builtin_amdgcn_mfma_f32_16x16x32_bf16(av, wfr[nt], acc[s][nt], 0, 0, 0);
        }
    }

    // ---- epilogue: vm = max over valid jj of (acc + g[j]); sigmoid; atomicMax ----
#pragma unroll
    for (int nt = 0; nt < 4; ++nt) {
        const int o = nt * 16 + li;
        float vm = -1e9f;
#pragma unroll
        for (int s = 0; s < 2; ++s)
#pragma unroll
            for (int r = 0; r < 4; ++r) {
                int jj = 16 * s + lg * 4 + r;
                float v = acc[s][nt][r] + gl[jj][o];
                if (!diag || (j0 + jj >= pi)) vm = fmaxf(vm, v);
            }
        vm = fmaxf(vm, __shfl_xor(vm, 16));
        vm = fmaxf(vm, __shfl_xor(vm, 32));
        if (l < 16) {
            float h = 1.0f / (1.0f + __expf(-vm));
            atomicMax((int*)out + (((size_t)(b * T_ + pi) << 6) + o), __float_as_int(h));
        }
    }
}

// ---------------------------------------------------------------------------
extern "C" void kernel_launch(void* const* d_in, const int* in_sizes, int n_in,
                              void* d_out, int out_size, void* d_ws, size_t ws_size,
                              hipStream_t stream) {
    const float* f  = (const float*)d_in[0];
    const float* W0 = (const float*)d_in[1];
    const float* b0 = (const float*)d_in[2];
    const float* W1 = (const float*)d_in[3];
    const float* b1 = (const float*)d_in[4];
    const float* W2 = (const float*)d_in[5];
    const float* b2 = (const float*)d_in[6];
    float* outp = (float*)d_out;

    // workspace layout
    unsigned short* tabmax = (unsigned short*)d_ws;               // 10*B*T*64
    unsigned short* tabmin = tabmax + 10 * B_ * T_ * 64;          // 10*B*T*64
    unsigned short* wf     = tabmin + 10 * B_ * T_ * 64;          // 3*16*64*8
    unsigned short* intra  = wf + 3 * 16 * 64 * 8;                // B*16*32*128
    float* cur1 = (float*)(intra + B_ * 16 * 32 * 128);           // [B,T,64]
    float* cur2 = cur1 + B_ * T_ * 64;                            // [B,T,64]
    float* gbuf = cur2 + B_ * T_ * 64;                            // [B,T,64]

    prep_kernel<<<dim3(139), dim3(512), 0, stream>>>(f, W0, W1, W2,
                                                     tabmax, tabmin, wf, intra,
                                                     cur1, cur2, outp);

    const dim3 pgrid(B_ * 544);
    const dim3 ggrid(B_ * T_ / 4);

    g0_kernel<<<ggrid, dim3(256), 0, stream>>>(tabmax, tabmin, W0, b0, gbuf);
    pair_kernel<<<pgrid, dim3(512), 0, stream>>>(tabmax, tabmin, intra,
                                                 wf + 0 * 8192, gbuf, cur1);

    g64_kernel<<<ggrid, dim3(256), 0, stream>>>(cur1, W1, b1, gbuf);
    pair_kernel<<<pgrid, dim3(512), 0, stream>>>(tabmax, tabmin, intra,
                                                 wf + 1 * 8192, gbuf, cur2);

    g64_kernel<<<ggrid, dim3(256), 0, stream>>>(cur2, W2, b2, gbuf);
    pair_kernel<<<pgrid, dim3(512), 0, stream>>>(tabmax, tabmin, intra,
                                                 wf + 2 * 8192, gbuf, outp);
}